// Round 6
// baseline (608.966 us; speedup 1.0000x reference)
//
#include <hip/hip_runtime.h>
#include <stdint.h>

typedef short bf16x8 __attribute__((ext_vector_type(8)));
typedef float f32x4 __attribute__((ext_vector_type(4)));
typedef float f32x16 __attribute__((ext_vector_type(16)));

__device__ __forceinline__ unsigned short f2bf(float f) {
  union { float f; unsigned int u; } v; v.f = f;
  unsigned int u = v.u;
  return (unsigned short)((u + 0x7FFFu + ((u >> 16) & 1u)) >> 16);  // RNE
}
__device__ __forceinline__ float bf2f(unsigned short u) {
  union { unsigned int u; float f; } v; v.u = ((unsigned int)u) << 16;
  return v.f;
}
__device__ __forceinline__ void async16(const void* g, void* l) {
  __builtin_amdgcn_global_load_lds(
      (const __attribute__((address_space(1))) unsigned int*)g,
      (__attribute__((address_space(3))) unsigned int*)l, 16, 0, 0);
}

// ---------------- cast f32 -> bf16, 8 elems/thread ----------------
__global__ __launch_bounds__(256) void cast_f32_bf16(
    const float* __restrict__ in, unsigned short* __restrict__ out, int n8) {
  int i = blockIdx.x * 256 + threadIdx.x;
  if (i >= n8) return;
  const float4* p = (const float4*)in;
  float4 a = p[2 * (size_t)i], b = p[2 * (size_t)i + 1];
  union { bf16x8 v; unsigned short s[8]; } o;
  o.s[0] = f2bf(a.x); o.s[1] = f2bf(a.y); o.s[2] = f2bf(a.z); o.s[3] = f2bf(a.w);
  o.s[4] = f2bf(b.x); o.s[5] = f2bf(b.y); o.s[6] = f2bf(b.z); o.s[7] = f2bf(b.w);
  *(bf16x8*)(out + 8 * (size_t)i) = o.v;
}

// stage one 16KB chunk (128 rows x 64 cols bf16) into linear LDS, 512 threads.
// Source pre-swizzled (16B chunk j of row r fetches global chunk j^(r&7)):
// swizzled reads then see correct data (both-sides-or-neither).
__device__ __forceinline__ void stage16k(const unsigned short* __restrict__ g0,
                                         int ldK, unsigned short* lds, int tid) {
#pragma unroll
  for (int q = 0; q < 2; ++q) {
    int idx = q * 512 + tid;
    int r = idx >> 3;                 // 0..127
    int jj = (idx & 7) ^ (r & 7);     // swizzled 16B chunk
    async16(g0 + (size_t)r * ldK + jj * 8,
            lds + ((size_t)(q * 512 + (tid & ~63))) * 8);  // wave-uniform base
  }
}

// C[m][n] = sum_k A[m0+m][ks*K + k] * B[n0+n][ks*K + k], both row-major lda.
// BM=BN=256, BK=64, 512 thr = 8 waves (2M x 4N), per-wave 128x64 out.
// 32x32x16 MFMA (2x work/issue vs 16x16x32 -> better pipe fill at 2 waves/SIMD).
// A triple-buffered, B double-buffered (160KB LDS); every chunk staged >=5
// phases before use; vmcnt(8) at ph3/ph7. K%128==0, K/128>=2.
// grid decode: mb = bid%mT (same-A blocks share an XCD), nb=(bid/mT)%nTn,
// ks = bid/(mT*nTn).
// OMODE: 1 = f32 out * (*scale_ptr), 2 = bf16 out at plane ks (split-K partial)
template <int OMODE>
__global__ __launch_bounds__(512, 2) void gemm256(
    const unsigned short* __restrict__ A, const unsigned short* __restrict__ B,
    void* __restrict__ Cv, int M, int N, int lda, int K,
    int nTn, int mT, const float* __restrict__ scale_ptr) {
  __shared__ __align__(16) unsigned short AsBuf[3][256 * 64];  // 96 KB
  __shared__ __align__(16) unsigned short BsBuf[2][256 * 64];  // 64 KB
  const int tid = threadIdx.x;
  const int w = tid >> 6, lane = tid & 63;
  int bid = blockIdx.x;
  const int mb = bid % mT; bid /= mT;
  const int nb = bid % nTn; const int ks = bid / nTn;
  const int m0 = mb * 256, n0 = nb * 256;
  const int wr = w >> 2, wc = w & 3;   // 2M x 4N waves
  const int R = K >> 7;                // iterations (pairs of K-tiles)

  const unsigned short* Ab = A + (size_t)m0 * lda + (size_t)ks * K;
  const unsigned short* Bb = B + (size_t)n0 * lda + (size_t)ks * K;

  unsigned short *a0 = AsBuf[0], *a1 = AsBuf[1], *a2 = AsBuf[2];
  unsigned short *b0 = BsBuf[0], *b1 = BsBuf[1];

  // prologue: A0,B0 then A1,B1 (16 loads/thread); vmcnt(8) -> A0,B0 landed
  stage16k(Ab,                          lda, a0,            tid);
  stage16k(Ab + (size_t)128 * lda,      lda, a0 + 128 * 64, tid);
  stage16k(Bb,                          lda, b0,            tid);
  stage16k(Bb + (size_t)128 * lda,      lda, b0 + 128 * 64, tid);
  stage16k(Ab + 64,                     lda, a1,            tid);
  stage16k(Ab + 64 + (size_t)128 * lda, lda, a1 + 128 * 64, tid);
  stage16k(Bb + 64,                     lda, b1,            tid);
  stage16k(Bb + 64 + (size_t)128 * lda, lda, b1 + 128 * 64, tid);
  asm volatile("s_waitcnt vmcnt(8)" ::: "memory");
  __builtin_amdgcn_s_barrier();
  asm volatile("" ::: "memory");

  const int l31 = lane & 31, lhi = lane >> 5;  // 32x32 frag: row/col=lane&31
  const int sa = l31 & 7;                      // swizzle key (rows mod 8)

  f32x16 acc[4][2] = {};  // [m-band q][n-tile nt], 128 VGPR

  for (int r = 0; r < R; ++r) {
    const bool st = (r + 1 < R);  // stage tiles 2r+2, 2r+3?
    bf16x8 bg[2][4];
#pragma unroll
    for (int ph = 0; ph < 8; ++ph) {
      const int d = ph >> 2, q = ph & 3;
      const char* cA = (const char*)(d == 0 ? a0 : a1);
      const char* cB = (const char*)(d == 0 ? b0 : b1);
      if (q == 0) {  // B-frags for this K-tile, register-resident 4 phases
#pragma unroll
        for (int nt = 0; nt < 2; ++nt) {
          const char* pb = cB + (wc * 64 + nt * 32 + l31) * 128;
#pragma unroll
          for (int ks2 = 0; ks2 < 4; ++ks2)
            bg[nt][ks2] = *(const bf16x8*)(pb + (((ks2 * 2 + lhi) ^ sa) << 4));
        }
      }
      bf16x8 af[4];
      const char* pa = cA + (wr * 128 + q * 32 + l31) * 128;
#pragma unroll
      for (int ks2 = 0; ks2 < 4; ++ks2)
        af[ks2] = *(const bf16x8*)(pa + (((ks2 * 2 + lhi) ^ sa) << 4));
      // uniform stage schedule: all targets free (last read >=1 barrier ago),
      // all consumers >=5 phases ahead (covers HBM latency).
      if (st) switch (ph) {
        case 0: stage16k(Ab + (size_t)(2 * r + 2) * 64, lda, a2, tid); break;
        case 1: stage16k(Ab + (size_t)(2 * r + 2) * 64 + (size_t)128 * lda, lda,
                         a2 + 128 * 64, tid); break;
        case 2: stage16k(Bb + (size_t)(2 * r + 2) * 64, lda, b0, tid); break;
        case 3: stage16k(Bb + (size_t)(2 * r + 2) * 64 + (size_t)128 * lda, lda,
                         b0 + 128 * 64, tid); break;
        case 4: stage16k(Ab + (size_t)(2 * r + 3) * 64, lda, a0, tid); break;
        case 5: stage16k(Ab + (size_t)(2 * r + 3) * 64 + (size_t)128 * lda, lda,
                         a0 + 128 * 64, tid); break;
        case 6: stage16k(Bb + (size_t)(2 * r + 3) * 64, lda, b1, tid); break;
        case 7: stage16k(Bb + (size_t)(2 * r + 3) * 64 + (size_t)128 * lda, lda,
                         b1 + 128 * 64, tid); break;
      }
      asm volatile("" ::: "memory");
      __builtin_amdgcn_s_barrier();
      asm volatile("" ::: "memory");
      __builtin_amdgcn_s_setprio(1);
#pragma unroll
      for (int ks2 = 0; ks2 < 4; ++ks2)   // ks outer: 2 independent acc chains
#pragma unroll
        for (int nt = 0; nt < 2; ++nt)
          acc[q][nt] = __builtin_amdgcn_mfma_f32_32x32x16_bf16(
              af[ks2], bg[nt][ks2], acc[q][nt], 0, 0, 0);
      __builtin_amdgcn_s_setprio(0);
      asm volatile("" ::: "memory");
      if (ph == 3) {
        // ph4 reads tiles staged last iter ph4-7 (8 loads = oldest outstanding)
        if (st) asm volatile("s_waitcnt vmcnt(8)" ::: "memory");
        else    asm volatile("s_waitcnt vmcnt(0)" ::: "memory");
      } else if (ph == 7) {
        // next iter ph0 reads tiles staged this iter ph0-3
        if (st) asm volatile("s_waitcnt vmcnt(8)" ::: "memory");
      }
      __builtin_amdgcn_s_barrier();
      asm volatile("" ::: "memory");
    }
    // A-buffer rotation: next iter low tile = a2, high = a0, stage target = a1
    unsigned short* t = a2; a2 = a1; a1 = a0; a0 = t;
  }

  float sc = 1.0f;
  if (OMODE == 1) sc = *scale_ptr;
  size_t base = (OMODE == 2) ? (size_t)ks * ((size_t)M * N) : 0;
  // 32x32 C/D layout (m74/m101): col = lane&31, row = (reg&3)+8*(reg>>2)+4*(lane>>5)
  const int rr0 = m0 + wr * 128 + lhi * 4;
  const int cc0 = n0 + wc * 64 + l31;
#pragma unroll
  for (int q = 0; q < 4; ++q)
#pragma unroll
    for (int nt = 0; nt < 2; ++nt)
#pragma unroll
      for (int reg = 0; reg < 16; ++reg) {
        int row = rr0 + q * 32 + (reg & 3) + 8 * (reg >> 2);
        size_t idx = base + (size_t)row * N + (cc0 + nt * 32);
        if (OMODE == 2) ((unsigned short*)Cv)[idx] = f2bf(acc[q][nt][reg]);
        else            ((float*)Cv)[idx] = acc[q][nt][reg] * sc;
      }
}

// ---- sum np bf16 planes -> bf16 (in-place safe) + init power vec & barrier ----
__global__ __launch_bounds__(256) void reduce_planes_init(
    const unsigned short* __restrict__ P, unsigned short* __restrict__ out,
    int n8, int np, size_t plane, float* __restrict__ t0,
    unsigned* __restrict__ cnt) {
  int i = blockIdx.x * 256 + threadIdx.x;
  if (blockIdx.x < 8) {  // init 2048-elem start vector (deterministic hash)
    int j = blockIdx.x * 256 + threadIdx.x;
    unsigned int h = (unsigned int)j * 2654435761u;
    h ^= h >> 16; h *= 2246822519u; h ^= h >> 13;
    t0[j] = (float)(h & 0xFFFFu) * (1.0f / 65536.0f) - 0.5f;
    if (j == 0) cnt[0] = 0u;
  }
  if (i >= n8) return;
  float s[8] = {0.f, 0.f, 0.f, 0.f, 0.f, 0.f, 0.f, 0.f};
  for (int p = 0; p < np; ++p) {
    bf16x8 v = *(const bf16x8*)(P + (size_t)p * plane + (size_t)i * 8);
#pragma unroll
    for (int j = 0; j < 8; ++j) s[j] += bf2f((unsigned short)v[j]);
  }
  union { bf16x8 v; unsigned short u[8]; } o;
#pragma unroll
  for (int j = 0; j < 8; ++j) o.u[j] = f2bf(s[j]);
  *(bf16x8*)(out + (size_t)i * 8) = o.v;
}

// ---------------- persistent shifted power iteration ----------------
// 22 iterations in ONE kernel: 5 unshifted, c = 0.49*||t5|| (computed
// redundantly per block, in-register), 17 shifted; then block 0 writes
// inv_scale. Grid-wide sync: monotonic-counter barrier (device-scope atomics).
// t ping-pong uses agent-scope atomic loads/stores (per-XCD L2 non-coherent).
// 256 blocks x 256 thr: all co-resident (capacity >> 256), no deadlock.
__global__ __launch_bounds__(256) void power_persist(
    const unsigned short* __restrict__ Am, float* __restrict__ tv,
    unsigned* __restrict__ cnt, float* __restrict__ inv_scale) {
  __shared__ __align__(16) float vs[2048];
  __shared__ float wred[4];
  const int tid = threadIdx.x;
  const int row = blockIdx.x * 8 + (tid >> 5);
  const int sub = tid & 31;
  const bf16x8* Ar = (const bf16x8*)(Am + (size_t)row * 2048);
  float c = 0.0f;

  for (int it = 0; it < 22; ++it) {
    const float* tin = tv + (it & 1) * 2048;
    float* tout = tv + ((it + 1) & 1) * 2048;
    float xv[8];
#pragma unroll
    for (int j = 0; j < 8; ++j)
      xv[j] = __hip_atomic_load(&tin[tid * 8 + j], __ATOMIC_RELAXED,
                                __HIP_MEMORY_SCOPE_AGENT);
    float ss = 0.f;
#pragma unroll
    for (int j = 0; j < 8; ++j) ss += xv[j] * xv[j];
#pragma unroll
    for (int o = 32; o > 0; o >>= 1) ss += __shfl_xor(ss, o);
    if ((tid & 63) == 0) wred[tid >> 6] = ss;
    __syncthreads();
    float nrm = sqrtf(wred[0] + wred[1] + wred[2] + wred[3]);
    if (it == 5) c = 0.49f * nrm;  // same value in every block (det. reduction)
    float inv = 1.0f / nrm;
#pragma unroll
    for (int j = 0; j < 8; ++j) vs[tid * 8 + j] = xv[j] * inv;
    __syncthreads();
    float s = 0.f;
#pragma unroll 2
    for (int cc = sub; cc < 256; cc += 32) {
      bf16x8 a = Ar[cc];
      float4 v0 = ((const float4*)vs)[2 * cc], v1 = ((const float4*)vs)[2 * cc + 1];
      s += bf2f((unsigned short)a[0]) * v0.x + bf2f((unsigned short)a[1]) * v0.y +
           bf2f((unsigned short)a[2]) * v0.z + bf2f((unsigned short)a[3]) * v0.w +
           bf2f((unsigned short)a[4]) * v1.x + bf2f((unsigned short)a[5]) * v1.y +
           bf2f((unsigned short)a[6]) * v1.z + bf2f((unsigned short)a[7]) * v1.w;
    }
#pragma unroll
    for (int o = 16; o > 0; o >>= 1) s += __shfl_xor(s, o);
    if (sub == 0)
      __hip_atomic_store(&tout[row], s - c * vs[row], __ATOMIC_RELAXED,
                         __HIP_MEMORY_SCOPE_AGENT);
    // grid barrier: monotonic counter, no reset needed (22*256 << 2^32)
    __syncthreads();
    if (tid == 0) {
      __threadfence();
      __hip_atomic_fetch_add(cnt, 1u, __ATOMIC_ACQ_REL, __HIP_MEMORY_SCOPE_AGENT);
      const unsigned tgt = (unsigned)(it + 1) * gridDim.x;
      while (__hip_atomic_load(cnt, __ATOMIC_ACQUIRE, __HIP_MEMORY_SCOPE_AGENT) < tgt)
        __builtin_amdgcn_s_sleep(2);
    }
    __syncthreads();
  }

  if (blockIdx.x == 0) {  // t22 = tv[0]; lambda1(A) ~= ||t22|| + c; sigma=sqrt
    float ss = 0.f;
#pragma unroll
    for (int j = 0; j < 8; ++j) {
      float v = __hip_atomic_load(&tv[tid * 8 + j], __ATOMIC_RELAXED,
                                  __HIP_MEMORY_SCOPE_AGENT);
      ss += v * v;
    }
#pragma unroll
    for (int o = 32; o > 0; o >>= 1) ss += __shfl_xor(ss, o);
    if ((tid & 63) == 0) wred[tid >> 6] = ss;
    __syncthreads();
    if (tid == 0) {
      float lam = sqrtf(wred[0] + wred[1] + wred[2] + wred[3]) + c;  // sigma^2
      float sigma = sqrtf(lam);
      inv_scale[0] = 1.0f / fmaxf(sigma, 1.0f);  // BOUND = 1.0
    }
  }
}

extern "C" void kernel_launch(void* const* d_in, const int* in_sizes, int n_in,
                              void* d_out, int out_size, void* d_ws, size_t ws_size,
                              hipStream_t stream) {
  (void)in_sizes; (void)n_in; (void)out_size; (void)ws_size;
  const float* x = (const float*)d_in[0];   // [8192, 2048]
  const float* W = (const float*)d_in[1];   // [2048, 2048]
  float* out = (float*)d_out;
  char* ws = (char*)d_ws;
  const int K = 2048, N = 2048, M = 4 * 2048;
  const size_t PLANE = (size_t)2048 * 2048;  // elems per bf16 plane (8 MB)

  unsigned short* xb = (unsigned short*)(ws);                       // 0-32 MB
  unsigned short* Wb = (unsigned short*)(ws + ((size_t)32 << 20));  // 32-40 MB
  unsigned short* P1 = (unsigned short*)(ws + ((size_t)40 << 20));  // 40-72 MB (4 planes)
  unsigned short* Am = P1;                                          // in-place reduce
  float* tv = (float*)(ws + ((size_t)72 << 20));
  float* inv_scale = tv + 4096;
  unsigned* cnt = (unsigned*)(tv + 4104);

  cast_f32_bf16<<<(M * K / 8 + 255) / 256, 256, 0, stream>>>(x, xb, M * K / 8);
  cast_f32_bf16<<<(N * K / 8 + 255) / 256, 256, 0, stream>>>(W, Wb, N * K / 8);

  // A = W W^T (sigma^2): split-K=4, grid 256
  gemm256<2><<<256, 512, 0, stream>>>(Wb, Wb, P1, 2048, 2048, 2048, 512, 8, 8, nullptr);
  reduce_planes_init<<<2048, 256, 0, stream>>>(P1, Am, (int)(PLANE / 8), 4, PLANE,
                                               tv, cnt);

  // shifted power iteration on A, single persistent kernel
  power_persist<<<256, 256, 0, stream>>>(Am, tv, cnt, inv_scale);

  // out = (x @ W^T) * inv_scale : grid 256, mT=32 (same-A blocks share an XCD)
  gemm256<1><<<256, 512, 0, stream>>>(xb, Wb, out, M, N, K, K, 8, 32, inv_scale);
}

// Round 7
// 201.837 us; speedup vs baseline: 3.0171x; 3.0171x over previous
//
#include <hip/hip_runtime.h>
#include <stdint.h>

typedef short bf16x8 __attribute__((ext_vector_type(8)));
typedef float f32x4 __attribute__((ext_vector_type(4)));
typedef float f32x16 __attribute__((ext_vector_type(16)));

__device__ __forceinline__ unsigned short f2bf(float f) {
  union { float f; unsigned int u; } v; v.f = f;
  unsigned int u = v.u;
  return (unsigned short)((u + 0x7FFFu + ((u >> 16) & 1u)) >> 16);  // RNE
}
__device__ __forceinline__ float bf2f(unsigned short u) {
  union { unsigned int u; float f; } v; v.u = ((unsigned int)u) << 16;
  return v.f;
}
__device__ __forceinline__ void async16(const void* g, void* l) {
  __builtin_amdgcn_global_load_lds(
      (const __attribute__((address_space(1))) unsigned int*)g,
      (__attribute__((address_space(3))) unsigned int*)l, 16, 0, 0);
}

// ---------------- cast f32 -> bf16, 8 elems/thread ----------------
__global__ __launch_bounds__(256) void cast_f32_bf16(
    const float* __restrict__ in, unsigned short* __restrict__ out, int n8) {
  int i = blockIdx.x * 256 + threadIdx.x;
  if (i >= n8) return;
  const float4* p = (const float4*)in;
  float4 a = p[2 * (size_t)i], b = p[2 * (size_t)i + 1];
  union { bf16x8 v; unsigned short s[8]; } o;
  o.s[0] = f2bf(a.x); o.s[1] = f2bf(a.y); o.s[2] = f2bf(a.z); o.s[3] = f2bf(a.w);
  o.s[4] = f2bf(b.x); o.s[5] = f2bf(b.y); o.s[6] = f2bf(b.z); o.s[7] = f2bf(b.w);
  *(bf16x8*)(out + 8 * (size_t)i) = o.v;
}

// stage one 16KB chunk (128 rows x 64 cols bf16) into linear LDS, 512 threads.
// Source pre-swizzled (16B chunk j of row r fetches global chunk j^(r&7)):
// swizzled reads then see correct data (both-sides-or-neither).
__device__ __forceinline__ void stage16k(const unsigned short* __restrict__ g0,
                                         int ldK, unsigned short* lds, int tid) {
#pragma unroll
  for (int q = 0; q < 2; ++q) {
    int idx = q * 512 + tid;
    int r = idx >> 3;                 // 0..127
    int jj = (idx & 7) ^ (r & 7);     // swizzled 16B chunk
    async16(g0 + (size_t)r * ldK + jj * 8,
            lds + ((size_t)(q * 512 + (tid & ~63))) * 8);  // wave-uniform base
  }
}

// C[m][n] = sum_k A[m0+m][ks*K + k] * B[n0+n][ks*K + k], both row-major lda.
// BM=BN=256, BK=64, 512 thr = 8 waves (2M x 4N), per-wave 128x64 out.
// 32x32x16 MFMA (2x work/issue vs 16x16x32 -> better pipe fill at 2 waves/SIMD).
// A triple-buffered, B double-buffered (160KB LDS); every chunk staged >=5
// phases before use; vmcnt(8) at ph3/ph7. K%128==0, K/128>=2.
// grid decode: mb = bid%mT (same-A blocks share an XCD), nb=(bid/mT)%nTn,
// ks = bid/(mT*nTn).
// OMODE: 1 = f32 out * (*scale_ptr), 2 = bf16 out at plane ks (split-K partial)
template <int OMODE>
__global__ __launch_bounds__(512, 2) void gemm256(
    const unsigned short* __restrict__ A, const unsigned short* __restrict__ B,
    void* __restrict__ Cv, int M, int N, int lda, int K,
    int nTn, int mT, const float* __restrict__ scale_ptr) {
  __shared__ __align__(16) unsigned short AsBuf[3][256 * 64];  // 96 KB
  __shared__ __align__(16) unsigned short BsBuf[2][256 * 64];  // 64 KB
  const int tid = threadIdx.x;
  const int w = tid >> 6, lane = tid & 63;
  int bid = blockIdx.x;
  const int mb = bid % mT; bid /= mT;
  const int nb = bid % nTn; const int ks = bid / nTn;
  const int m0 = mb * 256, n0 = nb * 256;
  const int wr = w >> 2, wc = w & 3;   // 2M x 4N waves
  const int R = K >> 7;                // iterations (pairs of K-tiles)

  const unsigned short* Ab = A + (size_t)m0 * lda + (size_t)ks * K;
  const unsigned short* Bb = B + (size_t)n0 * lda + (size_t)ks * K;

  unsigned short *a0 = AsBuf[0], *a1 = AsBuf[1], *a2 = AsBuf[2];
  unsigned short *b0 = BsBuf[0], *b1 = BsBuf[1];

  // prologue: A0,B0 then A1,B1 (16 loads/thread); vmcnt(8) -> A0,B0 landed
  stage16k(Ab,                          lda, a0,            tid);
  stage16k(Ab + (size_t)128 * lda,      lda, a0 + 128 * 64, tid);
  stage16k(Bb,                          lda, b0,            tid);
  stage16k(Bb + (size_t)128 * lda,      lda, b0 + 128 * 64, tid);
  stage16k(Ab + 64,                     lda, a1,            tid);
  stage16k(Ab + 64 + (size_t)128 * lda, lda, a1 + 128 * 64, tid);
  stage16k(Bb + 64,                     lda, b1,            tid);
  stage16k(Bb + 64 + (size_t)128 * lda, lda, b1 + 128 * 64, tid);
  asm volatile("s_waitcnt vmcnt(8)" ::: "memory");
  __builtin_amdgcn_s_barrier();
  asm volatile("" ::: "memory");

  const int l31 = lane & 31, lhi = lane >> 5;  // 32x32 frag: row/col=lane&31
  const int sa = l31 & 7;                      // swizzle key (rows mod 8)

  f32x16 acc[4][2] = {};  // [m-band q][n-tile nt], 128 VGPR

  for (int r = 0; r < R; ++r) {
    const bool st = (r + 1 < R);  // stage tiles 2r+2, 2r+3?
    bf16x8 bg[2][4];
#pragma unroll
    for (int ph = 0; ph < 8; ++ph) {
      const int d = ph >> 2, q = ph & 3;
      const char* cA = (const char*)(d == 0 ? a0 : a1);
      const char* cB = (const char*)(d == 0 ? b0 : b1);
      if (q == 0) {  // B-frags for this K-tile, register-resident 4 phases
#pragma unroll
        for (int nt = 0; nt < 2; ++nt) {
          const char* pb = cB + (wc * 64 + nt * 32 + l31) * 128;
#pragma unroll
          for (int ks2 = 0; ks2 < 4; ++ks2)
            bg[nt][ks2] = *(const bf16x8*)(pb + (((ks2 * 2 + lhi) ^ sa) << 4));
        }
      }
      bf16x8 af[4];
      const char* pa = cA + (wr * 128 + q * 32 + l31) * 128;
#pragma unroll
      for (int ks2 = 0; ks2 < 4; ++ks2)
        af[ks2] = *(const bf16x8*)(pa + (((ks2 * 2 + lhi) ^ sa) << 4));
      // uniform stage schedule: all targets free (last read >=1 barrier ago),
      // all consumers >=5 phases ahead (covers HBM latency).
      if (st) switch (ph) {
        case 0: stage16k(Ab + (size_t)(2 * r + 2) * 64, lda, a2, tid); break;
        case 1: stage16k(Ab + (size_t)(2 * r + 2) * 64 + (size_t)128 * lda, lda,
                         a2 + 128 * 64, tid); break;
        case 2: stage16k(Bb + (size_t)(2 * r + 2) * 64, lda, b0, tid); break;
        case 3: stage16k(Bb + (size_t)(2 * r + 2) * 64 + (size_t)128 * lda, lda,
                         b0 + 128 * 64, tid); break;
        case 4: stage16k(Ab + (size_t)(2 * r + 3) * 64, lda, a0, tid); break;
        case 5: stage16k(Ab + (size_t)(2 * r + 3) * 64 + (size_t)128 * lda, lda,
                         a0 + 128 * 64, tid); break;
        case 6: stage16k(Bb + (size_t)(2 * r + 3) * 64, lda, b1, tid); break;
        case 7: stage16k(Bb + (size_t)(2 * r + 3) * 64 + (size_t)128 * lda, lda,
                         b1 + 128 * 64, tid); break;
      }
      asm volatile("" ::: "memory");
      __builtin_amdgcn_s_barrier();
      asm volatile("" ::: "memory");
      __builtin_amdgcn_s_setprio(1);
#pragma unroll
      for (int ks2 = 0; ks2 < 4; ++ks2)   // ks outer: 2 independent acc chains
#pragma unroll
        for (int nt = 0; nt < 2; ++nt)
          acc[q][nt] = __builtin_amdgcn_mfma_f32_32x32x16_bf16(
              af[ks2], bg[nt][ks2], acc[q][nt], 0, 0, 0);
      __builtin_amdgcn_s_setprio(0);
      asm volatile("" ::: "memory");
      if (ph == 3) {
        // ph4 reads tiles staged last iter ph4-7 (8 loads = oldest outstanding)
        if (st) asm volatile("s_waitcnt vmcnt(8)" ::: "memory");
        else    asm volatile("s_waitcnt vmcnt(0)" ::: "memory");
      } else if (ph == 7) {
        // next iter ph0 reads tiles staged this iter ph0-3
        if (st) asm volatile("s_waitcnt vmcnt(8)" ::: "memory");
      }
      __builtin_amdgcn_s_barrier();
      asm volatile("" ::: "memory");
    }
    // A-buffer rotation: next iter low tile = a2, high = a0, stage target = a1
    unsigned short* t = a2; a2 = a1; a1 = a0; a0 = t;
  }

  float sc = 1.0f;
  if (OMODE == 1) sc = *scale_ptr;
  size_t base = (OMODE == 2) ? (size_t)ks * ((size_t)M * N) : 0;
  // 32x32 C/D layout (m74/m101): col = lane&31, row = (reg&3)+8*(reg>>2)+4*(lane>>5)
  const int rr0 = m0 + wr * 128 + lhi * 4;
  const int cc0 = n0 + wc * 64 + l31;
#pragma unroll
  for (int q = 0; q < 4; ++q)
#pragma unroll
    for (int nt = 0; nt < 2; ++nt)
#pragma unroll
      for (int reg = 0; reg < 16; ++reg) {
        int row = rr0 + q * 32 + (reg & 3) + 8 * (reg >> 2);
        size_t idx = base + (size_t)row * N + (cc0 + nt * 32);
        if (OMODE == 2) ((unsigned short*)Cv)[idx] = f2bf(acc[q][nt][reg]);
        else            ((float*)Cv)[idx] = acc[q][nt][reg] * sc;
      }
}

// ---- sum np bf16 planes -> bf16 (in-place safe) + init power vec & czero ----
__global__ __launch_bounds__(256) void reduce_planes_init(
    const unsigned short* __restrict__ P, unsigned short* __restrict__ out,
    int n8, int np, size_t plane, float* __restrict__ t0,
    float* __restrict__ czero) {
  int i = blockIdx.x * 256 + threadIdx.x;
  if (blockIdx.x < 8) {  // init 2048-elem start vector (deterministic hash)
    int j = blockIdx.x * 256 + threadIdx.x;
    unsigned int h = (unsigned int)j * 2654435761u;
    h ^= h >> 16; h *= 2246822519u; h ^= h >> 13;
    t0[j] = (float)(h & 0xFFFFu) * (1.0f / 65536.0f) - 0.5f;
    if (j == 0) czero[0] = 0.0f;
  }
  if (i >= n8) return;
  float s[8] = {0.f, 0.f, 0.f, 0.f, 0.f, 0.f, 0.f, 0.f};
  for (int p = 0; p < np; ++p) {
    bf16x8 v = *(const bf16x8*)(P + (size_t)p * plane + (size_t)i * 8);
#pragma unroll
    for (int j = 0; j < 8; ++j) s[j] += bf2f((unsigned short)v[j]);
  }
  union { bf16x8 v; unsigned short u[8]; } o;
#pragma unroll
  for (int j = 0; j < 8; ++j) o.u[j] = f2bf(s[j]);
  *(bf16x8*)(out + (size_t)i * 8) = o.v;
}

// ---------------- shifted power step: t_out = (A - c*I) * (t_in/||t_in||) ----
// MODE 0: c = *cptr.  MODE 1: c = 0.49*||t_in|| (computed in-register from the
// normalization pass; deterministic, identical in every block); block 0 also
// writes it to cwrite for subsequent launches.
template <int MODE>
__global__ __launch_bounds__(256) void power_step_bf16(
    const unsigned short* __restrict__ Am, const float* __restrict__ tin,
    float* __restrict__ tout, const float* __restrict__ cptr,
    float* __restrict__ cwrite) {
  __shared__ __align__(16) float vs[2048];
  __shared__ float wred[4];
  const int tid = threadIdx.x;
  float4 x0 = ((const float4*)tin)[2 * tid];
  float4 x1 = ((const float4*)tin)[2 * tid + 1];
  float ss = x0.x * x0.x + x0.y * x0.y + x0.z * x0.z + x0.w * x0.w +
             x1.x * x1.x + x1.y * x1.y + x1.z * x1.z + x1.w * x1.w;
#pragma unroll
  for (int o = 32; o > 0; o >>= 1) ss += __shfl_xor(ss, o);
  if ((tid & 63) == 0) wred[tid >> 6] = ss;
  __syncthreads();
  float nrm = sqrtf(wred[0] + wred[1] + wred[2] + wred[3]);
  float c;
  if (MODE == 1) {
    c = 0.49f * nrm;
    if (blockIdx.x == 0 && tid == 0) cwrite[0] = c;
  } else {
    c = cptr[0];
  }
  float inv = 1.0f / nrm;
  float4* vp = (float4*)vs;
  float4 y0 = {x0.x * inv, x0.y * inv, x0.z * inv, x0.w * inv};
  float4 y1 = {x1.x * inv, x1.y * inv, x1.z * inv, x1.w * inv};
  vp[2 * tid] = y0;
  vp[2 * tid + 1] = y1;
  __syncthreads();
  const int row = blockIdx.x * 8 + (tid >> 5);
  const int sub = tid & 31;
  const bf16x8* Ar = (const bf16x8*)(Am + (size_t)row * 2048);
  float s = 0.f;
#pragma unroll 2
  for (int cc = sub; cc < 256; cc += 32) {
    bf16x8 a = Ar[cc];
    float4 v0 = vp[2 * cc], v1 = vp[2 * cc + 1];
    s += bf2f((unsigned short)a[0]) * v0.x + bf2f((unsigned short)a[1]) * v0.y +
         bf2f((unsigned short)a[2]) * v0.z + bf2f((unsigned short)a[3]) * v0.w +
         bf2f((unsigned short)a[4]) * v1.x + bf2f((unsigned short)a[5]) * v1.y +
         bf2f((unsigned short)a[6]) * v1.z + bf2f((unsigned short)a[7]) * v1.w;
  }
#pragma unroll
  for (int o = 16; o > 0; o >>= 1) s += __shfl_xor(s, o);
  if (sub == 0) tout[row] = s - c * vs[row];
}

// lambda1(A) ~= ||t_k|| + c  (input was normalized); sigma = sqrt(lambda)
__global__ __launch_bounds__(256) void finalize_sigma(
    const float* __restrict__ tk, const float* __restrict__ cptr,
    float* __restrict__ inv_scale) {
  __shared__ float wred[4];
  const int tid = threadIdx.x;
  float4 x0 = ((const float4*)tk)[2 * tid];
  float4 x1 = ((const float4*)tk)[2 * tid + 1];
  float ss = x0.x * x0.x + x0.y * x0.y + x0.z * x0.z + x0.w * x0.w +
             x1.x * x1.x + x1.y * x1.y + x1.z * x1.z + x1.w * x1.w;
#pragma unroll
  for (int o = 32; o > 0; o >>= 1) ss += __shfl_xor(ss, o);
  if ((tid & 63) == 0) wred[tid >> 6] = ss;
  __syncthreads();
  if (tid == 0) {
    float lam = sqrtf(wred[0] + wred[1] + wred[2] + wred[3]) + cptr[0];  // sigma^2
    float sigma = sqrtf(lam);
    float scl = fmaxf(sigma, 1.0f);  // BOUND = 1.0
    inv_scale[0] = 1.0f / scl;
  }
}

extern "C" void kernel_launch(void* const* d_in, const int* in_sizes, int n_in,
                              void* d_out, int out_size, void* d_ws, size_t ws_size,
                              hipStream_t stream) {
  (void)in_sizes; (void)n_in; (void)out_size; (void)ws_size;
  const float* x = (const float*)d_in[0];   // [8192, 2048]
  const float* W = (const float*)d_in[1];   // [2048, 2048]
  float* out = (float*)d_out;
  char* ws = (char*)d_ws;
  const int K = 2048, N = 2048, M = 4 * 2048;
  const size_t PLANE = (size_t)2048 * 2048;  // elems per bf16 plane (8 MB)

  unsigned short* xb = (unsigned short*)(ws);                       // 0-32 MB
  unsigned short* Wb = (unsigned short*)(ws + ((size_t)32 << 20));  // 32-40 MB
  unsigned short* P1 = (unsigned short*)(ws + ((size_t)40 << 20));  // 40-72 MB (4 planes)
  unsigned short* Am = P1;                                          // in-place reduce
  float* tv = (float*)(ws + ((size_t)72 << 20));
  float* inv_scale = tv + 4096;
  float* czero = tv + 4097;
  float* cshift = tv + 4098;

  cast_f32_bf16<<<(M * K / 8 + 255) / 256, 256, 0, stream>>>(x, xb, M * K / 8);
  cast_f32_bf16<<<(N * K / 8 + 255) / 256, 256, 0, stream>>>(W, Wb, N * K / 8);

  // A = W W^T (sigma^2): split-K=4, grid 256
  gemm256<2><<<256, 512, 0, stream>>>(Wb, Wb, P1, 2048, 2048, 2048, 512, 8, 8, nullptr);
  reduce_planes_init<<<2048, 256, 0, stream>>>(P1, Am, (int)(PLANE / 8), 4, PLANE,
                                               tv, czero);

  // shifted power iteration on A: 5 unshifted, c=0.49*||t5|| (fused into step
  // 5), 16 more shifted steps
  int s = 0;
  for (; s < 5; ++s)
    power_step_bf16<0><<<256, 256, 0, stream>>>(Am, tv + (s & 1) * 2048,
                                                tv + ((s + 1) & 1) * 2048,
                                                czero, nullptr);
  power_step_bf16<1><<<256, 256, 0, stream>>>(Am, tv + (s & 1) * 2048,
                                              tv + ((s + 1) & 1) * 2048,
                                              czero, cshift);
  ++s;
  for (; s < 22; ++s)
    power_step_bf16<0><<<256, 256, 0, stream>>>(Am, tv + (s & 1) * 2048,
                                                tv + ((s + 1) & 1) * 2048,
                                                cshift, nullptr);
  finalize_sigma<<<1, 256, 0, stream>>>(tv + (s & 1) * 2048, cshift, inv_scale);

  // out = (x @ W^T) * inv_scale : grid 256, mT=32 (same-A blocks share an XCD)
  gemm256<1><<<256, 512, 0, stream>>>(xb, Wb, out, M, N, K, K, 8, 32, inv_scale);
}

// Round 8
// 200.724 us; speedup vs baseline: 3.0338x; 1.0055x over previous
//
#include <hip/hip_runtime.h>
#include <stdint.h>

typedef short bf16x8 __attribute__((ext_vector_type(8)));
typedef float f32x4 __attribute__((ext_vector_type(4)));

__device__ __forceinline__ unsigned short f2bf(float f) {
  union { float f; unsigned int u; } v; v.f = f;
  unsigned int u = v.u;
  return (unsigned short)((u + 0x7FFFu + ((u >> 16) & 1u)) >> 16);  // RNE
}
__device__ __forceinline__ float bf2f(unsigned short u) {
  union { unsigned int u; float f; } v; v.u = ((unsigned int)u) << 16;
  return v.f;
}
__device__ __forceinline__ void async16(const void* g, void* l) {
  __builtin_amdgcn_global_load_lds(
      (const __attribute__((address_space(1))) unsigned int*)g,
      (__attribute__((address_space(3))) unsigned int*)l, 16, 0, 0);
}
__device__ __forceinline__ void cast8(const float4 a, const float4 b,
                                      unsigned short* dst) {
  union { bf16x8 v; unsigned short s[8]; } o;
  o.s[0] = f2bf(a.x); o.s[1] = f2bf(a.y); o.s[2] = f2bf(a.z); o.s[3] = f2bf(a.w);
  o.s[4] = f2bf(b.x); o.s[5] = f2bf(b.y); o.s[6] = f2bf(b.z); o.s[7] = f2bf(b.w);
  *(bf16x8*)dst = o.v;
}

// ---------------- cast f32 -> bf16, 8 elems/thread (W only) ----------------
__global__ __launch_bounds__(256) void cast_f32_bf16(
    const float* __restrict__ in, unsigned short* __restrict__ out, int n8) {
  int i = blockIdx.x * 256 + threadIdx.x;
  if (i >= n8) return;
  const float4* p = (const float4*)in;
  cast8(p[2 * (size_t)i], p[2 * (size_t)i + 1], out + 8 * (size_t)i);
}

// stage one 16KB chunk (128 rows x 64 cols bf16) into linear LDS, 512 threads.
// Source pre-swizzled (16B chunk j of row r fetches global chunk j^(r&7)):
// swizzled reads then see correct data (both-sides-or-neither).
__device__ __forceinline__ void stage16k(const unsigned short* __restrict__ g0,
                                         int ldK, unsigned short* lds, int tid) {
#pragma unroll
  for (int q = 0; q < 2; ++q) {
    int idx = q * 512 + tid;
    int r = idx >> 3;                 // 0..127
    int jj = (idx & 7) ^ (r & 7);     // swizzled 16B chunk
    async16(g0 + (size_t)r * ldK + jj * 8,
            lds + ((size_t)(q * 512 + (tid & ~63))) * 8);  // wave-uniform base
  }
}

// C[m][n] = sum_k A[m0+m][ks*K + k] * B[n0+n][ks*K + k], both row-major lda.
// BM=BN=256, BK=64, 512 thr = 8 waves (2M x 4N), per-wave 128x64 out.
// 16x16x32 MFMA (R5-proven: 0 bank conflicts with this read pattern).
// A triple-buffered, B double-buffered (160KB LDS); every chunk staged >=5
// phases before use; vmcnt(8) at ph3/ph7. K%128==0, K/128>=2.
// grid decode: mb = bid%mT (same-A blocks share an XCD), nb=(bid/mT)%nTn,
// ks = bid/(mT*nTn).
// OMODE: 1 = f32 out * (*scale_ptr), 2 = bf16 out at plane ks (split-K partial)
template <int OMODE>
__global__ __launch_bounds__(512, 2) void gemm256(
    const unsigned short* __restrict__ A, const unsigned short* __restrict__ B,
    void* __restrict__ Cv, int M, int N, int lda, int K,
    int nTn, int mT, const float* __restrict__ scale_ptr) {
  __shared__ __align__(16) unsigned short AsBuf[3][256 * 64];  // 96 KB
  __shared__ __align__(16) unsigned short BsBuf[2][256 * 64];  // 64 KB
  const int tid = threadIdx.x;
  const int w = tid >> 6, lane = tid & 63;
  int bid = blockIdx.x;
  const int mb = bid % mT; bid /= mT;
  const int nb = bid % nTn; const int ks = bid / nTn;
  const int m0 = mb * 256, n0 = nb * 256;
  const int wr = w >> 2, wc = w & 3;   // 2M x 4N waves
  const int R = K >> 7;                // iterations (pairs of K-tiles)

  const unsigned short* Ab = A + (size_t)m0 * lda + (size_t)ks * K;
  const unsigned short* Bb = B + (size_t)n0 * lda + (size_t)ks * K;

  unsigned short *a0 = AsBuf[0], *a1 = AsBuf[1], *a2 = AsBuf[2];
  unsigned short *b0 = BsBuf[0], *b1 = BsBuf[1];

  // prologue: A0,B0 then A1,B1 (16 loads/thread); vmcnt(8) -> A0,B0 landed
  stage16k(Ab,                          lda, a0,            tid);
  stage16k(Ab + (size_t)128 * lda,      lda, a0 + 128 * 64, tid);
  stage16k(Bb,                          lda, b0,            tid);
  stage16k(Bb + (size_t)128 * lda,      lda, b0 + 128 * 64, tid);
  stage16k(Ab + 64,                     lda, a1,            tid);
  stage16k(Ab + 64 + (size_t)128 * lda, lda, a1 + 128 * 64, tid);
  stage16k(Bb + 64,                     lda, b1,            tid);
  stage16k(Bb + 64 + (size_t)128 * lda, lda, b1 + 128 * 64, tid);
  asm volatile("s_waitcnt vmcnt(8)" ::: "memory");
  __builtin_amdgcn_s_barrier();
  asm volatile("" ::: "memory");

  const int fr = lane & 15;
  const int bc0 = ((lane >> 4) << 4) ^ ((fr & 7) << 4);  // swizzled k-half 0
  const int bc1 = bc0 ^ 64;                              // k-half 1

  f32x4 acc[8][4] = {};

  for (int r = 0; r < R; ++r) {
    const bool st = (r + 1 < R);  // stage tiles 2r+2, 2r+3?
    bf16x8 bg[4][2];
#pragma unroll
    for (int ph = 0; ph < 8; ++ph) {
      const int d = ph >> 2, q = ph & 3;
      const char* cA = (const char*)(d == 0 ? a0 : a1);
      const char* cB = (const char*)(d == 0 ? b0 : b1);
      if (q == 0) {  // B-frags for this K-tile, register-resident 4 phases
#pragma unroll
        for (int nf = 0; nf < 4; ++nf) {
          int rb = (wc * 64 + nf * 16 + fr) * 128;
          bg[nf][0] = *(const bf16x8*)(cB + rb + bc0);
          bg[nf][1] = *(const bf16x8*)(cB + rb + bc1);
        }
      }
      bf16x8 af[2][2];
#pragma unroll
      for (int m2 = 0; m2 < 2; ++m2) {
        int rb = (wr * 128 + q * 32 + m2 * 16 + fr) * 128;
        af[m2][0] = *(const bf16x8*)(cA + rb + bc0);
        af[m2][1] = *(const bf16x8*)(cA + rb + bc1);
      }
      // uniform stage schedule: all targets free (last read >=1 barrier ago),
      // all consumers >=5 phases ahead (covers HBM latency).
      if (st) switch (ph) {
        case 0: stage16k(Ab + (size_t)(2 * r + 2) * 64, lda, a2, tid); break;
        case 1: stage16k(Ab + (size_t)(2 * r + 2) * 64 + (size_t)128 * lda, lda,
                         a2 + 128 * 64, tid); break;
        case 2: stage16k(Bb + (size_t)(2 * r + 2) * 64, lda, b0, tid); break;
        case 3: stage16k(Bb + (size_t)(2 * r + 2) * 64 + (size_t)128 * lda, lda,
                         b0 + 128 * 64, tid); break;
        case 4: stage16k(Ab + (size_t)(2 * r + 3) * 64, lda, a0, tid); break;
        case 5: stage16k(Ab + (size_t)(2 * r + 3) * 64 + (size_t)128 * lda, lda,
                         a0 + 128 * 64, tid); break;
        case 6: stage16k(Bb + (size_t)(2 * r + 3) * 64, lda, b1, tid); break;
        case 7: stage16k(Bb + (size_t)(2 * r + 3) * 64 + (size_t)128 * lda, lda,
                         b1 + 128 * 64, tid); break;
      }
      asm volatile("" ::: "memory");
      __builtin_amdgcn_s_barrier();
      asm volatile("" ::: "memory");
      __builtin_amdgcn_s_setprio(1);
#pragma unroll
      for (int m2 = 0; m2 < 2; ++m2)
#pragma unroll
        for (int nf = 0; nf < 4; ++nf)
#pragma unroll
          for (int kh = 0; kh < 2; ++kh)
            acc[q * 2 + m2][nf] = __builtin_amdgcn_mfma_f32_16x16x32_bf16(
                af[m2][kh], bg[nf][kh], acc[q * 2 + m2][nf], 0, 0, 0);
      __builtin_amdgcn_s_setprio(0);
      asm volatile("" ::: "memory");
      if (ph == 3) {
        // ph4 reads tiles staged last iter ph4-7 (8 loads = oldest outstanding)
        if (st) asm volatile("s_waitcnt vmcnt(8)" ::: "memory");
        else    asm volatile("s_waitcnt vmcnt(0)" ::: "memory");
      } else if (ph == 7) {
        // next iter ph0 reads tiles staged this iter ph0-3
        if (st) asm volatile("s_waitcnt vmcnt(8)" ::: "memory");
      }
      __builtin_amdgcn_s_barrier();
      asm volatile("" ::: "memory");
    }
    // A-buffer rotation: next iter low tile = a2, high = a0, stage target = a1
    unsigned short* t = a2; a2 = a1; a1 = a0; a0 = t;
  }

  float sc = 1.0f;
  if (OMODE == 1) sc = *scale_ptr;
  size_t base = (OMODE == 2) ? (size_t)ks * ((size_t)M * N) : 0;
  // C/D layout: col = lane&15, row = (lane>>4)*4 + reg (verified)
  const int rr0 = m0 + wr * 128 + ((lane >> 4) << 2);
  const int cc0 = n0 + wc * 64 + fr;
#pragma unroll
  for (int mf = 0; mf < 8; ++mf)
#pragma unroll
    for (int nf = 0; nf < 4; ++nf)
#pragma unroll
      for (int tt = 0; tt < 4; ++tt) {
        size_t idx = base + (size_t)(rr0 + mf * 16 + tt) * N + (cc0 + nf * 16);
        if (OMODE == 2) ((unsigned short*)Cv)[idx] = f2bf(acc[mf][nf][tt]);
        else            ((float*)Cv)[idx] = acc[mf][nf][tt] * sc;
      }
}

// ---- sum np bf16 planes -> bf16 (in-place safe) + init power vec & czero ----
__global__ __launch_bounds__(256) void reduce_planes_init(
    const unsigned short* __restrict__ P, unsigned short* __restrict__ out,
    int n8, int np, size_t plane, float* __restrict__ t0,
    float* __restrict__ czero) {
  int i = blockIdx.x * 256 + threadIdx.x;
  if (blockIdx.x < 8) {  // init 2048-elem start vector (deterministic hash)
    int j = blockIdx.x * 256 + threadIdx.x;
    unsigned int h = (unsigned int)j * 2654435761u;
    h ^= h >> 16; h *= 2246822519u; h ^= h >> 13;
    t0[j] = (float)(h & 0xFFFFu) * (1.0f / 65536.0f) - 0.5f;
    if (j == 0) czero[0] = 0.0f;
  }
  if (i >= n8) return;
  float s[8] = {0.f, 0.f, 0.f, 0.f, 0.f, 0.f, 0.f, 0.f};
  for (int p = 0; p < np; ++p) {
    bf16x8 v = *(const bf16x8*)(P + (size_t)p * plane + (size_t)i * 8);
#pragma unroll
    for (int j = 0; j < 8; ++j) s[j] += bf2f((unsigned short)v[j]);
  }
  union { bf16x8 v; unsigned short u[8]; } o;
#pragma unroll
  for (int j = 0; j < 8; ++j) o.u[j] = f2bf(s[j]);
  *(bf16x8*)(out + (size_t)i * 8) = o.v;
}

// ---------------- shifted power step: t_out = (A - c*I) * (t_in/||t_in||) ----
// MODE 0: c = *cptr.  MODE 1: c = 0.49*||t_in||; block 0 writes it to cwrite.
// Piggy-back: casts x[u0..u1) (8-elem units) f32->bf16. Loads issued at entry
// (independent of power path -> in flight under the GEMV), stores at the end.
template <int MODE>
__global__ __launch_bounds__(256) void power_step_bf16(
    const unsigned short* __restrict__ Am, const float* __restrict__ tin,
    float* __restrict__ tout, const float* __restrict__ cptr,
    float* __restrict__ cwrite, const float* __restrict__ xsrc,
    unsigned short* __restrict__ xdst, int u0, int u1) {
  __shared__ __align__(16) float vs[2048];
  __shared__ float wred[4];
  const int tid = threadIdx.x;

  // issue cast loads early (compile-time slots, <=2 units/thread)
  const int cu0 = u0 + blockIdx.x * 256 + tid;
  const int cu1 = cu0 + 65536;
  const bool cd0 = cu0 < u1, cd1 = cu1 < u1;
  float4 ca0, cb0, ca1, cb1;
  const float4* xp = (const float4*)xsrc;
  if (cd0) { ca0 = xp[2 * (size_t)cu0]; cb0 = xp[2 * (size_t)cu0 + 1]; }
  if (cd1) { ca1 = xp[2 * (size_t)cu1]; cb1 = xp[2 * (size_t)cu1 + 1]; }

  float4 x0 = ((const float4*)tin)[2 * tid];
  float4 x1 = ((const float4*)tin)[2 * tid + 1];
  float ss = x0.x * x0.x + x0.y * x0.y + x0.z * x0.z + x0.w * x0.w +
             x1.x * x1.x + x1.y * x1.y + x1.z * x1.z + x1.w * x1.w;
#pragma unroll
  for (int o = 32; o > 0; o >>= 1) ss += __shfl_xor(ss, o);
  if ((tid & 63) == 0) wred[tid >> 6] = ss;
  __syncthreads();
  float nrm = sqrtf(wred[0] + wred[1] + wred[2] + wred[3]);
  float c;
  if (MODE == 1) {
    c = 0.49f * nrm;
    if (blockIdx.x == 0 && tid == 0) cwrite[0] = c;
  } else {
    c = cptr[0];
  }
  float inv = 1.0f / nrm;
  float4* vp = (float4*)vs;
  float4 y0 = {x0.x * inv, x0.y * inv, x0.z * inv, x0.w * inv};
  float4 y1 = {x1.x * inv, x1.y * inv, x1.z * inv, x1.w * inv};
  vp[2 * tid] = y0;
  vp[2 * tid + 1] = y1;
  __syncthreads();
  const int row = blockIdx.x * 8 + (tid >> 5);
  const int sub = tid & 31;
  const bf16x8* Ar = (const bf16x8*)(Am + (size_t)row * 2048);
  float s = 0.f;
#pragma unroll 2
  for (int cc = sub; cc < 256; cc += 32) {
    bf16x8 a = Ar[cc];
    float4 v0 = vp[2 * cc], v1 = vp[2 * cc + 1];
    s += bf2f((unsigned short)a[0]) * v0.x + bf2f((unsigned short)a[1]) * v0.y +
         bf2f((unsigned short)a[2]) * v0.z + bf2f((unsigned short)a[3]) * v0.w +
         bf2f((unsigned short)a[4]) * v1.x + bf2f((unsigned short)a[5]) * v1.y +
         bf2f((unsigned short)a[6]) * v1.z + bf2f((unsigned short)a[7]) * v1.w;
  }
#pragma unroll
  for (int o = 16; o > 0; o >>= 1) s += __shfl_xor(s, o);
  if (sub == 0) tout[row] = s - c * vs[row];

  // distributed x-cast writeback
  if (cd0) cast8(ca0, cb0, xdst + 8 * (size_t)cu0);
  if (cd1) cast8(ca1, cb1, xdst + 8 * (size_t)cu1);
}

// lambda1(A) ~= ||t_k|| + c  (input was normalized); sigma = sqrt(lambda)
__global__ __launch_bounds__(256) void finalize_sigma(
    const float* __restrict__ tk, const float* __restrict__ cptr,
    float* __restrict__ inv_scale) {
  __shared__ float wred[4];
  const int tid = threadIdx.x;
  float4 x0 = ((const float4*)tk)[2 * tid];
  float4 x1 = ((const float4*)tk)[2 * tid + 1];
  float ss = x0.x * x0.x + x0.y * x0.y + x0.z * x0.z + x0.w * x0.w +
             x1.x * x1.x + x1.y * x1.y + x1.z * x1.z + x1.w * x1.w;
#pragma unroll
  for (int o = 32; o > 0; o >>= 1) ss += __shfl_xor(ss, o);
  if ((tid & 63) == 0) wred[tid >> 6] = ss;
  __syncthreads();
  if (tid == 0) {
    float lam = sqrtf(wred[0] + wred[1] + wred[2] + wred[3]) + cptr[0];  // sigma^2
    float sigma = sqrtf(lam);
    float scl = fmaxf(sigma, 1.0f);  // BOUND = 1.0
    inv_scale[0] = 1.0f / scl;
  }
}

extern "C" void kernel_launch(void* const* d_in, const int* in_sizes, int n_in,
                              void* d_out, int out_size, void* d_ws, size_t ws_size,
                              hipStream_t stream) {
  (void)in_sizes; (void)n_in; (void)out_size; (void)ws_size;
  const float* x = (const float*)d_in[0];   // [8192, 2048]
  const float* W = (const float*)d_in[1];   // [2048, 2048]
  float* out = (float*)d_out;
  char* ws = (char*)d_ws;
  const int K = 2048, N = 2048, M = 4 * 2048;
  const size_t PLANE = (size_t)2048 * 2048;  // elems per bf16 plane (8 MB)

  unsigned short* xb = (unsigned short*)(ws);                       // 0-32 MB
  unsigned short* Wb = (unsigned short*)(ws + ((size_t)32 << 20));  // 32-40 MB
  unsigned short* P1 = (unsigned short*)(ws + ((size_t)40 << 20));  // 40-72 MB (4 planes)
  unsigned short* Am = P1;                                          // in-place reduce
  float* tv = (float*)(ws + ((size_t)72 << 20));
  float* inv_scale = tv + 4096;
  float* czero = tv + 4097;
  float* cshift = tv + 4098;

  // W-cast only; x-cast is distributed across the 22 power-step launches
  cast_f32_bf16<<<(N * K / 8 + 255) / 256, 256, 0, stream>>>(W, Wb, N * K / 8);

  // A = W W^T (sigma^2): split-K=4, grid 256
  gemm256<2><<<256, 512, 0, stream>>>(Wb, Wb, P1, 2048, 2048, 2048, 512, 8, 8, nullptr);
  reduce_planes_init<<<2048, 256, 0, stream>>>(P1, Am, (int)(PLANE / 8), 4, PLANE,
                                               tv, czero);

  // shifted power iteration on A: 5 unshifted, c=0.49*||t5|| (fused into step
  // 5), 16 more shifted steps. Each launch also casts a slice of x.
  const int XU = M * K / 8;                 // 2,097,152 cast units
  const int CH = (XU + 21) / 22;            // per-launch slice
  int s = 0;
  for (; s < 5; ++s)
    power_step_bf16<0><<<256, 256, 0, stream>>>(
        Am, tv + (s & 1) * 2048, tv + ((s + 1) & 1) * 2048, czero, nullptr,
        x, xb, s * CH, min((s + 1) * CH, XU));
  power_step_bf16<1><<<256, 256, 0, stream>>>(
      Am, tv + (s & 1) * 2048, tv + ((s + 1) & 1) * 2048, czero, cshift,
      x, xb, s * CH, min((s + 1) * CH, XU));
  ++s;
  for (; s < 22; ++s)
    power_step_bf16<0><<<256, 256, 0, stream>>>(
        Am, tv + (s & 1) * 2048, tv + ((s + 1) & 1) * 2048, cshift, nullptr,
        x, xb, s * CH, min((s + 1) * CH, XU));
  finalize_sigma<<<1, 256, 0, stream>>>(tv + (s & 1) * 2048, cshift, inv_scale);

  // out = (x @ W^T) * inv_scale : grid 256, mT=32 (same-A blocks share an XCD)
  gemm256<1><<<256, 512, 0, stream>>>(xb, Wb, out, M, N, K, K, 8, 32, inv_scale);
}

// Round 9
// 172.604 us; speedup vs baseline: 3.5281x; 1.1629x over previous
//
#include <hip/hip_runtime.h>
#include <stdint.h>

typedef short bf16x8 __attribute__((ext_vector_type(8)));
typedef float f32x4 __attribute__((ext_vector_type(4)));

__device__ __forceinline__ unsigned short f2bf(float f) {
  union { float f; unsigned int u; } v; v.f = f;
  unsigned int u = v.u;
  return (unsigned short)((u + 0x7FFFu + ((u >> 16) & 1u)) >> 16);  // RNE
}
__device__ __forceinline__ float bf2f(unsigned short u) {
  union { unsigned int u; float f; } v; v.u = ((unsigned int)u) << 16;
  return v.f;
}
__device__ __forceinline__ void async16(const void* g, void* l) {
  __builtin_amdgcn_global_load_lds(
      (const __attribute__((address_space(1))) unsigned int*)g,
      (__attribute__((address_space(3))) unsigned int*)l, 16, 0, 0);
}
__device__ __forceinline__ void cast8(const float4 a, const float4 b,
                                      unsigned short* dst) {
  union { bf16x8 v; unsigned short s[8]; } o;
  o.s[0] = f2bf(a.x); o.s[1] = f2bf(a.y); o.s[2] = f2bf(a.z); o.s[3] = f2bf(a.w);
  o.s[4] = f2bf(b.x); o.s[5] = f2bf(b.y); o.s[6] = f2bf(b.z); o.s[7] = f2bf(b.w);
  *(bf16x8*)dst = o.v;
}
__device__ __forceinline__ float dot8(bf16x8 a, float4 v0, float4 v1) {
  return bf2f((unsigned short)a[0]) * v0.x + bf2f((unsigned short)a[1]) * v0.y +
         bf2f((unsigned short)a[2]) * v0.z + bf2f((unsigned short)a[3]) * v0.w +
         bf2f((unsigned short)a[4]) * v1.x + bf2f((unsigned short)a[5]) * v1.y +
         bf2f((unsigned short)a[6]) * v1.z + bf2f((unsigned short)a[7]) * v1.w;
}

// ---------------- cast f32 -> bf16, 8 elems/thread (W only) ----------------
__global__ __launch_bounds__(256) void cast_f32_bf16(
    const float* __restrict__ in, unsigned short* __restrict__ out, int n8) {
  int i = blockIdx.x * 256 + threadIdx.x;
  if (i >= n8) return;
  const float4* p = (const float4*)in;
  cast8(p[2 * (size_t)i], p[2 * (size_t)i + 1], out + 8 * (size_t)i);
}

// stage one 16KB chunk (128 rows x 64 cols bf16) into linear LDS, 512 threads.
// Source pre-swizzled (16B chunk j of row r fetches global chunk j^(r&7)):
// swizzled reads then see correct data (both-sides-or-neither).
__device__ __forceinline__ void stage16k(const unsigned short* __restrict__ g0,
                                         int ldK, unsigned short* lds, int tid) {
#pragma unroll
  for (int q = 0; q < 2; ++q) {
    int idx = q * 512 + tid;
    int r = idx >> 3;                 // 0..127
    int jj = (idx & 7) ^ (r & 7);     // swizzled 16B chunk
    async16(g0 + (size_t)r * ldK + jj * 8,
            lds + ((size_t)(q * 512 + (tid & ~63))) * 8);  // wave-uniform base
  }
}

// C[m][n] = sum_k A[m0+m][ks*K + k] * B[n0+n][ks*K + k], both row-major lda.
// BM=BN=256, BK=64, 512 thr = 8 waves (2M x 4N), per-wave 128x64 out.
// 16x16x32 MFMA (R5-proven: 0 bank conflicts with this read pattern).
// A triple-buffered, B double-buffered (160KB LDS); every chunk staged >=5
// phases before use; vmcnt(8) at ph3/ph7. K%128==0, K/128>=2.
// grid decode: mb = bid%mT (same-A blocks share an XCD), nb=(bid/mT)%nTn,
// ks = bid/(mT*nTn).
// OMODE: 1 = f32 out * (*scale_ptr), 2 = bf16 out at plane ks (split-K partial)
template <int OMODE>
__global__ __launch_bounds__(512, 2) void gemm256(
    const unsigned short* __restrict__ A, const unsigned short* __restrict__ B,
    void* __restrict__ Cv, int M, int N, int lda, int K,
    int nTn, int mT, const float* __restrict__ scale_ptr) {
  __shared__ __align__(16) unsigned short AsBuf[3][256 * 64];  // 96 KB
  __shared__ __align__(16) unsigned short BsBuf[2][256 * 64];  // 64 KB
  const int tid = threadIdx.x;
  const int w = tid >> 6, lane = tid & 63;
  int bid = blockIdx.x;
  const int mb = bid % mT; bid /= mT;
  const int nb = bid % nTn; const int ks = bid / nTn;
  const int m0 = mb * 256, n0 = nb * 256;
  const int wr = w >> 2, wc = w & 3;   // 2M x 4N waves
  const int R = K >> 7;                // iterations (pairs of K-tiles)

  const unsigned short* Ab = A + (size_t)m0 * lda + (size_t)ks * K;
  const unsigned short* Bb = B + (size_t)n0 * lda + (size_t)ks * K;

  unsigned short *a0 = AsBuf[0], *a1 = AsBuf[1], *a2 = AsBuf[2];
  unsigned short *b0 = BsBuf[0], *b1 = BsBuf[1];

  // prologue: A0,B0 then A1,B1 (16 loads/thread); vmcnt(8) -> A0,B0 landed
  stage16k(Ab,                          lda, a0,            tid);
  stage16k(Ab + (size_t)128 * lda,      lda, a0 + 128 * 64, tid);
  stage16k(Bb,                          lda, b0,            tid);
  stage16k(Bb + (size_t)128 * lda,      lda, b0 + 128 * 64, tid);
  stage16k(Ab + 64,                     lda, a1,            tid);
  stage16k(Ab + 64 + (size_t)128 * lda, lda, a1 + 128 * 64, tid);
  stage16k(Bb + 64,                     lda, b1,            tid);
  stage16k(Bb + 64 + (size_t)128 * lda, lda, b1 + 128 * 64, tid);
  asm volatile("s_waitcnt vmcnt(8)" ::: "memory");
  __builtin_amdgcn_s_barrier();
  asm volatile("" ::: "memory");

  const int fr = lane & 15;
  const int bc0 = ((lane >> 4) << 4) ^ ((fr & 7) << 4);  // swizzled k-half 0
  const int bc1 = bc0 ^ 64;                              // k-half 1

  f32x4 acc[8][4] = {};

  for (int r = 0; r < R; ++r) {
    const bool st = (r + 1 < R);  // stage tiles 2r+2, 2r+3?
    bf16x8 bg[4][2];
#pragma unroll
    for (int ph = 0; ph < 8; ++ph) {
      const int d = ph >> 2, q = ph & 3;
      const char* cA = (const char*)(d == 0 ? a0 : a1);
      const char* cB = (const char*)(d == 0 ? b0 : b1);
      if (q == 0) {  // B-frags for this K-tile, register-resident 4 phases
#pragma unroll
        for (int nf = 0; nf < 4; ++nf) {
          int rb = (wc * 64 + nf * 16 + fr) * 128;
          bg[nf][0] = *(const bf16x8*)(cB + rb + bc0);
          bg[nf][1] = *(const bf16x8*)(cB + rb + bc1);
        }
      }
      bf16x8 af[2][2];
#pragma unroll
      for (int m2 = 0; m2 < 2; ++m2) {
        int rb = (wr * 128 + q * 32 + m2 * 16 + fr) * 128;
        af[m2][0] = *(const bf16x8*)(cA + rb + bc0);
        af[m2][1] = *(const bf16x8*)(cA + rb + bc1);
      }
      // uniform stage schedule: all targets free (last read >=1 barrier ago),
      // all consumers >=5 phases ahead (covers HBM latency).
      if (st) switch (ph) {
        case 0: stage16k(Ab + (size_t)(2 * r + 2) * 64, lda, a2, tid); break;
        case 1: stage16k(Ab + (size_t)(2 * r + 2) * 64 + (size_t)128 * lda, lda,
                         a2 + 128 * 64, tid); break;
        case 2: stage16k(Bb + (size_t)(2 * r + 2) * 64, lda, b0, tid); break;
        case 3: stage16k(Bb + (size_t)(2 * r + 2) * 64 + (size_t)128 * lda, lda,
                         b0 + 128 * 64, tid); break;
        case 4: stage16k(Ab + (size_t)(2 * r + 3) * 64, lda, a0, tid); break;
        case 5: stage16k(Ab + (size_t)(2 * r + 3) * 64 + (size_t)128 * lda, lda,
                         a0 + 128 * 64, tid); break;
        case 6: stage16k(Bb + (size_t)(2 * r + 3) * 64, lda, b1, tid); break;
        case 7: stage16k(Bb + (size_t)(2 * r + 3) * 64 + (size_t)128 * lda, lda,
                         b1 + 128 * 64, tid); break;
      }
      asm volatile("" ::: "memory");
      __builtin_amdgcn_s_barrier();
      asm volatile("" ::: "memory");
      __builtin_amdgcn_s_setprio(1);
#pragma unroll
      for (int m2 = 0; m2 < 2; ++m2)
#pragma unroll
        for (int nf = 0; nf < 4; ++nf)
#pragma unroll
          for (int kh = 0; kh < 2; ++kh)
            acc[q * 2 + m2][nf] = __builtin_amdgcn_mfma_f32_16x16x32_bf16(
                af[m2][kh], bg[nf][kh], acc[q * 2 + m2][nf], 0, 0, 0);
      __builtin_amdgcn_s_setprio(0);
      asm volatile("" ::: "memory");
      if (ph == 3) {
        // ph4 reads tiles staged last iter ph4-7 (8 loads = oldest outstanding)
        if (st) asm volatile("s_waitcnt vmcnt(8)" ::: "memory");
        else    asm volatile("s_waitcnt vmcnt(0)" ::: "memory");
      } else if (ph == 7) {
        // next iter ph0 reads tiles staged this iter ph0-3
        if (st) asm volatile("s_waitcnt vmcnt(8)" ::: "memory");
      }
      __builtin_amdgcn_s_barrier();
      asm volatile("" ::: "memory");
    }
    // A-buffer rotation: next iter low tile = a2, high = a0, stage target = a1
    unsigned short* t = a2; a2 = a1; a1 = a0; a0 = t;
  }

  float sc = 1.0f;
  if (OMODE == 1) sc = *scale_ptr;
  size_t base = (OMODE == 2) ? (size_t)ks * ((size_t)M * N) : 0;
  // C/D layout: col = lane&15, row = (lane>>4)*4 + reg (verified)
  const int rr0 = m0 + wr * 128 + ((lane >> 4) << 2);
  const int cc0 = n0 + wc * 64 + fr;
#pragma unroll
  for (int mf = 0; mf < 8; ++mf)
#pragma unroll
    for (int nf = 0; nf < 4; ++nf)
#pragma unroll
      for (int tt = 0; tt < 4; ++tt) {
        size_t idx = base + (size_t)(rr0 + mf * 16 + tt) * N + (cc0 + nf * 16);
        if (OMODE == 2) ((unsigned short*)Cv)[idx] = f2bf(acc[mf][nf][tt]);
        else            ((float*)Cv)[idx] = acc[mf][nf][tt] * sc;
      }
}

// ---- sum np bf16 planes -> bf16 (in-place safe) + init power vec & czero ----
__global__ __launch_bounds__(256) void reduce_planes_init(
    const unsigned short* __restrict__ P, unsigned short* __restrict__ out,
    int n8, int np, size_t plane, float* __restrict__ t0,
    float* __restrict__ czero) {
  int i = blockIdx.x * 256 + threadIdx.x;
  if (blockIdx.x < 8) {  // init 2048-elem start vector (deterministic hash)
    int j = blockIdx.x * 256 + threadIdx.x;
    unsigned int h = (unsigned int)j * 2654435761u;
    h ^= h >> 16; h *= 2246822519u; h ^= h >> 13;
    t0[j] = (float)(h & 0xFFFFu) * (1.0f / 65536.0f) - 0.5f;
    if (j == 0) czero[0] = 0.0f;
  }
  if (i >= n8) return;
  float s[8] = {0.f, 0.f, 0.f, 0.f, 0.f, 0.f, 0.f, 0.f};
  for (int p = 0; p < np; ++p) {
    bf16x8 v = *(const bf16x8*)(P + (size_t)p * plane + (size_t)i * 8);
#pragma unroll
    for (int j = 0; j < 8; ++j) s[j] += bf2f((unsigned short)v[j]);
  }
  union { bf16x8 v; unsigned short u[8]; } o;
#pragma unroll
  for (int j = 0; j < 8; ++j) o.u[j] = f2bf(s[j]);
  *(bf16x8*)(out + (size_t)i * 8) = o.v;
}

// ---------------- GEMV step on A (2048x2048 bf16), 256 blocks x 512 thr ----
// 8 rows/block, 64 lanes/row, 4x 16B row-loads/lane issued at ENTRY (latency
// hidden under the norm phase). Piggy-backs a 1-unit/thread x f32->bf16 cast.
// MODE 0 (plain):  v = tin/||tin||;          tout[row] = (A v)[row]
// MODE 2 (cheb-init): rho=||tin||; v=tin/rho; tout[row] = (2/rho)(Av)[row]-v[row];
//                   aux[row] = v[row] (y0 for the next step); ch[0] = rho (blk 0)
// MODE 3 (cheb):   v = tin (raw);            tout[row] = (4/ch)(Av)[row]
//                                                        - 2 v[row] - aux[row]
template <int MODE>
__global__ __launch_bounds__(512) void gemv_step(
    const unsigned short* __restrict__ Am, const float* __restrict__ tin,
    float* __restrict__ tout, float* __restrict__ ch, float* __restrict__ aux,
    const float* __restrict__ xsrc, unsigned short* __restrict__ xdst,
    int u0, int u1) {
  __shared__ __align__(16) float vs[2048];
  __shared__ float wred[8];
  const int tid = threadIdx.x;
  const int wv = tid >> 6, lane = tid & 63;
  const int row = blockIdx.x * 8 + wv;

  // early-issue: A-row chunks (independent of the norm path -> in flight now)
  const bf16x8* Ar = (const bf16x8*)(Am + (size_t)row * 2048);
  bf16x8 ar0 = Ar[lane], ar1 = Ar[lane + 64];
  bf16x8 ar2 = Ar[lane + 128], ar3 = Ar[lane + 192];
  // early-issue: x-cast slice (exactly 1 unit/thread)
  const int cu = u0 + blockIdx.x * 512 + tid;
  const bool cd = cu < u1;
  float4 ca, cb;
  if (cd) {
    ca = ((const float4*)xsrc)[2 * (size_t)cu];
    cb = ((const float4*)xsrc)[2 * (size_t)cu + 1];
  }
  float ymv = 0.f, chv = 0.f;
  if (MODE == 3) { ymv = aux[row]; chv = ch[0]; }

  float4 x0 = ((const float4*)tin)[tid];
  float sin_ = 1.0f;
  if (MODE != 3) {  // redundant deterministic norm (identical in every block)
    float ss = x0.x * x0.x + x0.y * x0.y + x0.z * x0.z + x0.w * x0.w;
#pragma unroll
    for (int o = 32; o > 0; o >>= 1) ss += __shfl_xor(ss, o);
    if (lane == 0) wred[wv] = ss;
    __syncthreads();
    float n2 = 0.f;
#pragma unroll
    for (int j = 0; j < 8; ++j) n2 += wred[j];
    float nrm = sqrtf(n2);
    if (MODE == 2) {
      chv = nrm;
      if (blockIdx.x == 0 && tid == 0) ch[0] = nrm;
    }
    sin_ = 1.0f / nrm;
  }
  float4 y = {x0.x * sin_, x0.y * sin_, x0.z * sin_, x0.w * sin_};
  ((float4*)vs)[tid] = y;
  __syncthreads();

  const float4* vp = (const float4*)vs;
  float s = dot8(ar0, vp[2 * lane], vp[2 * lane + 1]);
  s += dot8(ar1, vp[2 * (lane + 64)], vp[2 * (lane + 64) + 1]);
  s += dot8(ar2, vp[2 * (lane + 128)], vp[2 * (lane + 128) + 1]);
  s += dot8(ar3, vp[2 * (lane + 192)], vp[2 * (lane + 192) + 1]);
#pragma unroll
  for (int o = 32; o > 0; o >>= 1) s += __shfl_xor(s, o);
  if (lane == 0) {
    float r;
    if (MODE == 0)      r = s;
    else if (MODE == 2) r = (2.0f / chv) * s - vs[row];
    else                r = (4.0f / chv) * s - 2.0f * vs[row] - ymv;
    tout[row] = r;
    if (MODE == 2) aux[row] = vs[row];  // y0 (normalized) for first cheb step
  }
  // distributed x-cast writeback
  if (cd) cast8(ca, cb, xdst + 8 * (size_t)cu);
}

// lambda1(A) ~= ||t_k|| + c (input was normalized); sigma = sqrt(lambda)
__global__ __launch_bounds__(256) void finalize_sigma(
    const float* __restrict__ tk, const float* __restrict__ cptr,
    float* __restrict__ inv_scale) {
  __shared__ float wred[4];
  const int tid = threadIdx.x;
  float4 x0 = ((const float4*)tk)[2 * tid];
  float4 x1 = ((const float4*)tk)[2 * tid + 1];
  float ss = x0.x * x0.x + x0.y * x0.y + x0.z * x0.z + x0.w * x0.w +
             x1.x * x1.x + x1.y * x1.y + x1.z * x1.z + x1.w * x1.w;
#pragma unroll
  for (int o = 32; o > 0; o >>= 1) ss += __shfl_xor(ss, o);
  if ((tid & 63) == 0) wred[tid >> 6] = ss;
  __syncthreads();
  if (tid == 0) {
    float lam = sqrtf(wred[0] + wred[1] + wred[2] + wred[3]) + cptr[0];  // sigma^2
    float sigma = sqrtf(lam);
    float scl = fmaxf(sigma, 1.0f);  // BOUND = 1.0
    inv_scale[0] = 1.0f / scl;
  }
}

extern "C" void kernel_launch(void* const* d_in, const int* in_sizes, int n_in,
                              void* d_out, int out_size, void* d_ws, size_t ws_size,
                              hipStream_t stream) {
  (void)in_sizes; (void)n_in; (void)out_size; (void)ws_size;
  const float* x = (const float*)d_in[0];   // [8192, 2048]
  const float* W = (const float*)d_in[1];   // [2048, 2048]
  float* out = (float*)d_out;
  char* ws = (char*)d_ws;
  const int K = 2048, N = 2048, M = 4 * 2048;
  const size_t PLANE = (size_t)2048 * 2048;  // elems per bf16 plane (8 MB)

  unsigned short* xb = (unsigned short*)(ws);                       // 0-32 MB
  unsigned short* Wb = (unsigned short*)(ws + ((size_t)32 << 20));  // 32-40 MB
  unsigned short* P1 = (unsigned short*)(ws + ((size_t)40 << 20));  // 40-72 MB (4 planes)
  unsigned short* Am = P1;                                          // in-place reduce
  float* tv = (float*)(ws + ((size_t)72 << 20));
  float* tb0 = tv, *tb1 = tv + 2048, *tb2 = tv + 4096;
  float* inv_scale = tv + 6144;
  float* czero = tv + 6145;
  float* cshift = tv + 6146;
  float* tb[3] = {tb0, tb1, tb2};

  // W-cast only; x-cast is distributed across the 18 GEMV launches
  cast_f32_bf16<<<(N * K / 8 + 255) / 256, 256, 0, stream>>>(W, Wb, N * K / 8);

  // A = W W^T (sigma^2): split-K=4, grid 256
  gemm256<2><<<256, 512, 0, stream>>>(Wb, Wb, P1, 2048, 2048, 2048, 512, 8, 8, nullptr);
  reduce_planes_init<<<2048, 256, 0, stream>>>(P1, Am, (int)(PLANE / 8), 4, PLANE,
                                               tb0, czero);

  // sigma estimation: 3 rough power steps -> lambda_hat -> Chebyshev x13 ->
  // plain extraction GEMV. 18 GEMV launches total, each casts an x slice.
  const int XU = M * K / 8;             // 2,097,152 cast units
  const int NL = 18;
  const int CH = (XU + NL - 1) / NL;    // per-launch slice
  int li = 0;
#define SLICE x, xb, (li) * CH, min((li + 1) * CH, XU)); ++li
  gemv_step<0><<<256, 512, 0, stream>>>(Am, tb0, tb1, cshift, czero, SLICE;
  gemv_step<0><<<256, 512, 0, stream>>>(Am, tb1, tb0, cshift, czero, SLICE;
  gemv_step<0><<<256, 512, 0, stream>>>(Am, tb0, tb1, cshift, czero, SLICE;
  // cheb init: y0 = t3/||t3|| (saved to tb0), y1 -> tb2, ch = ||t3||
  gemv_step<2><<<256, 512, 0, stream>>>(Am, tb1, tb2, cshift, tb0, SLICE;
  int cy = 2, cm = 0;
  for (int k = 0; k < 13; ++k) {
    int co = 3 - cy - cm;
    gemv_step<3><<<256, 512, 0, stream>>>(Am, tb[cy], tb[co], cshift, tb[cm], SLICE;
    cm = cy; cy = co;
  }
  // extraction: u = A * (y_last/||y_last||); lambda = ||u||
  int co = 3 - cy - cm;
  gemv_step<0><<<256, 512, 0, stream>>>(Am, tb[cy], tb[co], cshift, czero, SLICE;
#undef SLICE
  finalize_sigma<<<1, 256, 0, stream>>>(tb[co], czero, inv_scale);

  // out = (x @ W^T) * inv_scale : grid 256, mT=32 (same-A blocks share an XCD)
  gemm256<1><<<256, 512, 0, stream>>>(xb, Wb, out, M, N, K, K, 8, 32, inv_scale);
}

// Round 11
// 170.083 us; speedup vs baseline: 3.5804x; 1.0148x over previous
//
#include <hip/hip_runtime.h>
#include <stdint.h>

typedef short bf16x8 __attribute__((ext_vector_type(8)));
typedef float f32x4 __attribute__((ext_vector_type(4)));

__device__ __forceinline__ unsigned short f2bf(float f) {
  union { float f; unsigned int u; } v; v.f = f;
  unsigned int u = v.u;
  return (unsigned short)((u + 0x7FFFu + ((u >> 16) & 1u)) >> 16);  // RNE
}
__device__ __forceinline__ float bf2f(unsigned short u) {
  union { unsigned int u; float f; } v; v.u = ((unsigned int)u) << 16;
  return v.f;
}
__device__ __forceinline__ void async16(const void* g, void* l) {
  __builtin_amdgcn_global_load_lds(
      (const __attribute__((address_space(1))) unsigned int*)g,
      (__attribute__((address_space(3))) unsigned int*)l, 16, 0, 0);
}
__device__ __forceinline__ void cast8(const float4 a, const float4 b,
                                      unsigned short* dst) {
  union { bf16x8 v; unsigned short s[8]; } o;
  o.s[0] = f2bf(a.x); o.s[1] = f2bf(a.y); o.s[2] = f2bf(a.z); o.s[3] = f2bf(a.w);
  o.s[4] = f2bf(b.x); o.s[5] = f2bf(b.y); o.s[6] = f2bf(b.z); o.s[7] = f2bf(b.w);
  *(bf16x8*)dst = o.v;
}
__device__ __forceinline__ float dot8(bf16x8 a, float4 v0, float4 v1) {
  return bf2f((unsigned short)a[0]) * v0.x + bf2f((unsigned short)a[1]) * v0.y +
         bf2f((unsigned short)a[2]) * v0.z + bf2f((unsigned short)a[3]) * v0.w +
         bf2f((unsigned short)a[4]) * v1.x + bf2f((unsigned short)a[5]) * v1.y +
         bf2f((unsigned short)a[6]) * v1.z + bf2f((unsigned short)a[7]) * v1.w;
}

// ---------------- cast f32 -> bf16, 8 elems/thread (W only) ----------------
__global__ __launch_bounds__(256) void cast_f32_bf16(
    const float* __restrict__ in, unsigned short* __restrict__ out, int n8) {
  int i = blockIdx.x * 256 + threadIdx.x;
  if (i >= n8) return;
  const float4* p = (const float4*)in;
  cast8(p[2 * (size_t)i], p[2 * (size_t)i + 1], out + 8 * (size_t)i);
}

// stage one 16KB chunk (128 rows x 64 cols bf16) into linear LDS, 512 threads.
// Source pre-swizzled (16B chunk j of row r fetches global chunk j^(r&7)):
// swizzled reads then see correct data (both-sides-or-neither).
__device__ __forceinline__ void stage16k(const unsigned short* __restrict__ g0,
                                         int ldK, unsigned short* lds, int tid) {
#pragma unroll
  for (int q = 0; q < 2; ++q) {
    int idx = q * 512 + tid;
    int r = idx >> 3;                 // 0..127
    int jj = (idx & 7) ^ (r & 7);     // swizzled 16B chunk
    async16(g0 + (size_t)r * ldK + jj * 8,
            lds + ((size_t)(q * 512 + (tid & ~63))) * 8);  // wave-uniform base
  }
}

// C[m][n] = sum_k A[m0+m][ks*K + k] * B[n0+n][ks*K + k], both row-major lda.
// BM=BN=256, BK=64, 512 thr = 8 waves (2M x 4N), per-wave 128x64 out.
// 16x16x32 MFMA (R5-proven: 0 bank conflicts with this read pattern).
// A triple-buffered, B double-buffered (160KB LDS); every chunk staged >=5
// phases before use; vmcnt(8) at ph3/ph7. K%128==0, K/128>=2.
// grid decode: mb = bid%mT (same-A blocks share an XCD), nb=(bid/mT)%nTn,
// ks = bid/(mT*nTn).
// OMODE: 1 = f32 out * (*scale_ptr), 2 = bf16 out at plane ks (split-K partial)
template <int OMODE>
__global__ __launch_bounds__(512, 2) void gemm256(
    const unsigned short* __restrict__ A, const unsigned short* __restrict__ B,
    void* __restrict__ Cv, int M, int N, int lda, int K,
    int nTn, int mT, const float* __restrict__ scale_ptr) {
  __shared__ __align__(16) unsigned short AsBuf[3][256 * 64];  // 96 KB
  __shared__ __align__(16) unsigned short BsBuf[2][256 * 64];  // 64 KB
  const int tid = threadIdx.x;
  const int w = tid >> 6, lane = tid & 63;
  int bid = blockIdx.x;
  const int mb = bid % mT; bid /= mT;
  const int nb = bid % nTn; const int ks = bid / nTn;
  const int m0 = mb * 256, n0 = nb * 256;
  const int wr = w >> 2, wc = w & 3;   // 2M x 4N waves
  const int R = K >> 7;                // iterations (pairs of K-tiles)

  const unsigned short* Ab = A + (size_t)m0 * lda + (size_t)ks * K;
  const unsigned short* Bb = B + (size_t)n0 * lda + (size_t)ks * K;

  unsigned short *a0 = AsBuf[0], *a1 = AsBuf[1], *a2 = AsBuf[2];
  unsigned short *b0 = BsBuf[0], *b1 = BsBuf[1];

  // prologue: A0,B0 then A1,B1 (16 loads/thread); vmcnt(8) -> A0,B0 landed
  stage16k(Ab,                          lda, a0,            tid);
  stage16k(Ab + (size_t)128 * lda,      lda, a0 + 128 * 64, tid);
  stage16k(Bb,                          lda, b0,            tid);
  stage16k(Bb + (size_t)128 * lda,      lda, b0 + 128 * 64, tid);
  stage16k(Ab + 64,                     lda, a1,            tid);
  stage16k(Ab + 64 + (size_t)128 * lda, lda, a1 + 128 * 64, tid);
  stage16k(Bb + 64,                     lda, b1,            tid);
  stage16k(Bb + 64 + (size_t)128 * lda, lda, b1 + 128 * 64, tid);
  asm volatile("s_waitcnt vmcnt(8)" ::: "memory");
  __builtin_amdgcn_s_barrier();
  asm volatile("" ::: "memory");

  const int fr = lane & 15;
  const int bc0 = ((lane >> 4) << 4) ^ ((fr & 7) << 4);  // swizzled k-half 0
  const int bc1 = bc0 ^ 64;                              // k-half 1

  f32x4 acc[8][4] = {};

  for (int r = 0; r < R; ++r) {
    const bool st = (r + 1 < R);  // stage tiles 2r+2, 2r+3?
    bf16x8 bg[4][2];
#pragma unroll
    for (int ph = 0; ph < 8; ++ph) {
      const int d = ph >> 2, q = ph & 3;
      const char* cA = (const char*)(d == 0 ? a0 : a1);
      const char* cB = (const char*)(d == 0 ? b0 : b1);
      if (q == 0) {  // B-frags for this K-tile, register-resident 4 phases
#pragma unroll
        for (int nf = 0; nf < 4; ++nf) {
          int rb = (wc * 64 + nf * 16 + fr) * 128;
          bg[nf][0] = *(const bf16x8*)(cB + rb + bc0);
          bg[nf][1] = *(const bf16x8*)(cB + rb + bc1);
        }
      }
      bf16x8 af[2][2];
#pragma unroll
      for (int m2 = 0; m2 < 2; ++m2) {
        int rb = (wr * 128 + q * 32 + m2 * 16 + fr) * 128;
        af[m2][0] = *(const bf16x8*)(cA + rb + bc0);
        af[m2][1] = *(const bf16x8*)(cA + rb + bc1);
      }
      // uniform stage schedule: all targets free (last read >=1 barrier ago),
      // all consumers >=5 phases ahead (covers HBM latency).
      if (st) switch (ph) {
        case 0: stage16k(Ab + (size_t)(2 * r + 2) * 64, lda, a2, tid); break;
        case 1: stage16k(Ab + (size_t)(2 * r + 2) * 64 + (size_t)128 * lda, lda,
                         a2 + 128 * 64, tid); break;
        case 2: stage16k(Bb + (size_t)(2 * r + 2) * 64, lda, b0, tid); break;
        case 3: stage16k(Bb + (size_t)(2 * r + 2) * 64 + (size_t)128 * lda, lda,
                         b0 + 128 * 64, tid); break;
        case 4: stage16k(Ab + (size_t)(2 * r + 3) * 64, lda, a0, tid); break;
        case 5: stage16k(Ab + (size_t)(2 * r + 3) * 64 + (size_t)128 * lda, lda,
                         a0 + 128 * 64, tid); break;
        case 6: stage16k(Bb + (size_t)(2 * r + 3) * 64, lda, b1, tid); break;
        case 7: stage16k(Bb + (size_t)(2 * r + 3) * 64 + (size_t)128 * lda, lda,
                         b1 + 128 * 64, tid); break;
      }
      asm volatile("" ::: "memory");
      __builtin_amdgcn_s_barrier();
      asm volatile("" ::: "memory");
      __builtin_amdgcn_s_setprio(1);
#pragma unroll
      for (int m2 = 0; m2 < 2; ++m2)
#pragma unroll
        for (int nf = 0; nf < 4; ++nf)
#pragma unroll
          for (int kh = 0; kh < 2; ++kh)
            acc[q * 2 + m2][nf] = __builtin_amdgcn_mfma_f32_16x16x32_bf16(
                af[m2][kh], bg[nf][kh], acc[q * 2 + m2][nf], 0, 0, 0);
      __builtin_amdgcn_s_setprio(0);
      asm volatile("" ::: "memory");
      if (ph == 3) {
        // ph4 reads tiles staged last iter ph4-7 (8 loads = oldest outstanding)
        if (st) asm volatile("s_waitcnt vmcnt(8)" ::: "memory");
        else    asm volatile("s_waitcnt vmcnt(0)" ::: "memory");
      } else if (ph == 7) {
        // next iter ph0 reads tiles staged this iter ph0-3
        if (st) asm volatile("s_waitcnt vmcnt(8)" ::: "memory");
      }
      __builtin_amdgcn_s_barrier();
      asm volatile("" ::: "memory");
    }
    // A-buffer rotation: next iter low tile = a2, high = a0, stage target = a1
    unsigned short* t = a2; a2 = a1; a1 = a0; a0 = t;
  }

  float sc = 1.0f;
  if (OMODE == 1) sc = *scale_ptr;
  size_t base = (OMODE == 2) ? (size_t)ks * ((size_t)M * N) : 0;
  // C/D layout: col = lane&15, row = (lane>>4)*4 + reg (verified)
  const int rr0 = m0 + wr * 128 + ((lane >> 4) << 2);
  const int cc0 = n0 + wc * 64 + fr;
#pragma unroll
  for (int mf = 0; mf < 8; ++mf)
#pragma unroll
    for (int nf = 0; nf < 4; ++nf)
#pragma unroll
      for (int tt = 0; tt < 4; ++tt) {
        size_t idx = base + (size_t)(rr0 + mf * 16 + tt) * N + (cc0 + nf * 16);
        if (OMODE == 2) ((unsigned short*)Cv)[idx] = f2bf(acc[mf][nf][tt]);
        else            ((float*)Cv)[idx] = acc[mf][nf][tt] * sc;
      }
}

// ---- fused: reduce 4 split-K planes -> Am (bf16, in-place on plane 0),
// ---- init t0 (hash, normalized), and rough power step #1: tout = A_sum v0.
// 256 blocks x 512 thr; block handles 8 rows; per (row,chunk) one owner lane
// (reads of all 4 planes precede the in-place write -> no hazard).
__global__ __launch_bounds__(512) void gemv_first(
    const unsigned short* __restrict__ P, unsigned short* __restrict__ Aout,
    size_t plane, float* __restrict__ tout) {
  __shared__ __align__(16) float vs[2048];
  __shared__ float wred[8];
  const int tid = threadIdx.x;
  const int wv = tid >> 6, lane = tid & 63;
  const int row = blockIdx.x * 8 + wv;

  // t0 via deterministic hash (4 elems/thread), redundant per-block norm
  float t0[4]; float ss = 0.f;
#pragma unroll
  for (int j = 0; j < 4; ++j) {
    int idx = tid * 4 + j;
    unsigned int h = (unsigned int)idx * 2654435761u;
    h ^= h >> 16; h *= 2246822519u; h ^= h >> 13;
    t0[j] = (float)(h & 0xFFFFu) * (1.0f / 65536.0f) - 0.5f;
    ss += t0[j] * t0[j];
  }
#pragma unroll
  for (int o = 32; o > 0; o >>= 1) ss += __shfl_xor(ss, o);
  if (lane == 0) wred[wv] = ss;
  __syncthreads();
  float n2 = 0.f;
#pragma unroll
  for (int j = 0; j < 8; ++j) n2 += wred[j];
  float inv = 1.0f / sqrtf(n2);
#pragma unroll
  for (int j = 0; j < 4; ++j) vs[tid * 4 + j] = t0[j] * inv;
  __syncthreads();

  const size_t rbase = (size_t)row * 2048;
  float s = 0.f;
#pragma unroll
  for (int c4 = 0; c4 < 4; ++c4) {
    int c = lane + c4 * 64;  // 16B chunk index 0..255 within the row
    float a8[8] = {0.f, 0.f, 0.f, 0.f, 0.f, 0.f, 0.f, 0.f};
#pragma unroll
    for (int p = 0; p < 4; ++p) {
      bf16x8 v = *(const bf16x8*)(P + p * plane + rbase + (size_t)c * 8);
#pragma unroll
      for (int j = 0; j < 8; ++j) a8[j] += bf2f((unsigned short)v[j]);
    }
    union { bf16x8 v; unsigned short u[8]; } o;
#pragma unroll
    for (int j = 0; j < 8; ++j) o.u[j] = f2bf(a8[j]);
    *(bf16x8*)(Aout + rbase + (size_t)c * 8) = o.v;
    float4 v0 = ((const float4*)vs)[2 * c], v1 = ((const float4*)vs)[2 * c + 1];
    s += a8[0] * v0.x + a8[1] * v0.y + a8[2] * v0.z + a8[3] * v0.w +
         a8[4] * v1.x + a8[5] * v1.y + a8[6] * v1.z + a8[7] * v1.w;
  }
#pragma unroll
  for (int o = 32; o > 0; o >>= 1) s += __shfl_xor(s, o);
  if (lane == 0) tout[row] = s;
}

// ---------------- GEMV step on A (2048x2048 bf16), 256 blocks x 512 thr ----
// 8 rows/block, 64 lanes/row, 4x 16B row-loads/lane issued at ENTRY (latency
// hidden under the norm phase). Piggy-backs a 2-unit/thread x f32->bf16 cast.
// MODE 0 (plain):  v = tin/||tin||;          tout[row] = (A v)[row]
// MODE 2 (cheb-init): rho=||tin||; v=tin/rho; tout[row] = (2/rho)(Av)[row]-v[row];
//                   aux[row] = v[row] (y0 for the next step); ch[0] = rho (blk 0)
// MODE 3 (cheb):   v = tin (raw);            tout[row] = (4/ch)(Av)[row]
//                                                        - 2 v[row] - aux[row]
template <int MODE>
__global__ __launch_bounds__(512) void gemv_step(
    const unsigned short* __restrict__ Am, const float* __restrict__ tin,
    float* __restrict__ tout, float* __restrict__ ch, float* __restrict__ aux,
    const float* __restrict__ xsrc, unsigned short* __restrict__ xdst,
    int u0, int u1) {
  __shared__ __align__(16) float vs[2048];
  __shared__ float wred[8];
  const int tid = threadIdx.x;
  const int wv = tid >> 6, lane = tid & 63;
  const int row = blockIdx.x * 8 + wv;

  // early-issue: A-row chunks (independent of the norm path -> in flight now)
  const bf16x8* Ar = (const bf16x8*)(Am + (size_t)row * 2048);
  bf16x8 ar0 = Ar[lane], ar1 = Ar[lane + 64];
  bf16x8 ar2 = Ar[lane + 128], ar3 = Ar[lane + 192];
  // early-issue: x-cast slice (2 guarded units/thread)
  const int cu0 = u0 + blockIdx.x * 512 + tid;
  const int cu1 = cu0 + 131072;
  const bool cd0 = cu0 < u1, cd1 = cu1 < u1;
  float4 ca0, cb0, ca1, cb1;
  const float4* xp = (const float4*)xsrc;
  if (cd0) { ca0 = xp[2 * (size_t)cu0]; cb0 = xp[2 * (size_t)cu0 + 1]; }
  if (cd1) { ca1 = xp[2 * (size_t)cu1]; cb1 = xp[2 * (size_t)cu1 + 1]; }

  float ymv = 0.f, chv = 0.f;
  if (MODE == 3) { ymv = aux[row]; chv = ch[0]; }

  float4 x0 = ((const float4*)tin)[tid];
  float sin_ = 1.0f;
  if (MODE != 3) {  // redundant deterministic norm (identical in every block)
    float ss = x0.x * x0.x + x0.y * x0.y + x0.z * x0.z + x0.w * x0.w;
#pragma unroll
    for (int o = 32; o > 0; o >>= 1) ss += __shfl_xor(ss, o);
    if (lane == 0) wred[wv] = ss;
    __syncthreads();
    float n2 = 0.f;
#pragma unroll
    for (int j = 0; j < 8; ++j) n2 += wred[j];
    float nrm = sqrtf(n2);
    if (MODE == 2) {
      chv = nrm;
      if (blockIdx.x == 0 && tid == 0) ch[0] = nrm;
    }
    sin_ = 1.0f / nrm;
  }
  float4 y = {x0.x * sin_, x0.y * sin_, x0.z * sin_, x0.w * sin_};
  ((float4*)vs)[tid] = y;
  __syncthreads();

  const float4* vp = (const float4*)vs;
  float s = dot8(ar0, vp[2 * lane], vp[2 * lane + 1]);
  s += dot8(ar1, vp[2 * (lane + 64)], vp[2 * (lane + 64) + 1]);
  s += dot8(ar2, vp[2 * (lane + 128)], vp[2 * (lane + 128) + 1]);
  s += dot8(ar3, vp[2 * (lane + 192)], vp[2 * (lane + 192) + 1]);
#pragma unroll
  for (int o = 32; o > 0; o >>= 1) s += __shfl_xor(s, o);
  if (lane == 0) {
    float r;
    if (MODE == 0)      r = s;
    else if (MODE == 2) r = (2.0f / chv) * s - vs[row];
    else                r = (4.0f / chv) * s - 2.0f * vs[row] - ymv;
    tout[row] = r;
    if (MODE == 2) aux[row] = vs[row];  // y0 (normalized) for first cheb step
  }
  // distributed x-cast writeback
  if (cd0) cast8(ca0, cb0, xdst + 8 * (size_t)cu0);
  if (cd1) cast8(ca1, cb1, xdst + 8 * (size_t)cu1);
}

// lambda1(A) ~= ||u|| where u = A v, ||v||=1; sigma = sqrt(lambda)
__global__ __launch_bounds__(256) void finalize_sigma(
    const float* __restrict__ tk, float* __restrict__ inv_scale) {
  __shared__ float wred[4];
  const int tid = threadIdx.x;
  float4 x0 = ((const float4*)tk)[2 * tid];
  float4 x1 = ((const float4*)tk)[2 * tid + 1];
  float ss = x0.x * x0.x + x0.y * x0.y + x0.z * x0.z + x0.w * x0.w +
             x1.x * x1.x + x1.y * x1.y + x1.z * x1.z + x1.w * x1.w;
#pragma unroll
  for (int o = 32; o > 0; o >>= 1) ss += __shfl_xor(ss, o);
  if ((tid & 63) == 0) wred[tid >> 6] = ss;
  __syncthreads();
  if (tid == 0) {
    float lam = sqrtf(wred[0] + wred[1] + wred[2] + wred[3]);  // sigma^2
    float sigma = sqrtf(lam);
    float scl = fmaxf(sigma, 1.0f);  // BOUND = 1.0
    inv_scale[0] = 1.0f / scl;
  }
}

extern "C" void kernel_launch(void* const* d_in, const int* in_sizes, int n_in,
                              void* d_out, int out_size, void* d_ws, size_t ws_size,
                              hipStream_t stream) {
  (void)in_sizes; (void)n_in; (void)out_size; (void)ws_size;
  const float* x = (const float*)d_in[0];   // [8192, 2048]
  const float* W = (const float*)d_in[1];   // [2048, 2048]
  float* out = (float*)d_out;
  char* ws = (char*)d_ws;
  const int K = 2048, N = 2048, M = 4 * 2048;
  const size_t PLANE = (size_t)2048 * 2048;  // elems per bf16 plane (8 MB)

  unsigned short* xb = (unsigned short*)(ws);                       // 0-32 MB
  unsigned short* Wb = (unsigned short*)(ws + ((size_t)32 << 20));  // 32-40 MB
  unsigned short* P1 = (unsigned short*)(ws + ((size_t)40 << 20));  // 40-72 MB (4 planes)
  unsigned short* Am = P1;                                          // in-place reduce
  float* tv = (float*)(ws + ((size_t)72 << 20));
  float* tb0 = tv, *tb1 = tv + 2048, *tb2 = tv + 4096;
  float* inv_scale = tv + 6144;
  float* cshift = tv + 6146;
  float* tb[3] = {tb0, tb1, tb2};

  // W-cast only; x-cast is distributed across the 17 light GEMV launches
  cast_f32_bf16<<<(N * K / 8 + 255) / 256, 256, 0, stream>>>(W, Wb, N * K / 8);

  // A = W W^T (sigma^2): split-K=4, grid 256
  gemm256<2><<<256, 512, 0, stream>>>(Wb, Wb, P1, 2048, 2048, 2048, 512, 8, 8, nullptr);
  // fused plane-reduce + t0 init + rough power step #1 -> tb1
  gemv_first<<<256, 512, 0, stream>>>(P1, Am, PLANE, tb1);

  // sigma estimation (R9-proven depth): rough #2, #3 -> cheb-init
  // (lambda_hat = ||t3||) -> 13x cheb -> extraction GEMV. 17 light launches.
  const int XU = M * K / 8;             // 2,097,152 cast units
  const int NL = 17;
  const int CH = (XU + NL - 1) / NL;    // per-launch slice
  int li = 0;
#define SLICE x, xb, (li) * CH, min((li + 1) * CH, XU)); ++li
  gemv_step<0><<<256, 512, 0, stream>>>(Am, tb1, tb0, cshift, tb2, SLICE;  // t2
  gemv_step<0><<<256, 512, 0, stream>>>(Am, tb0, tb1, cshift, tb2, SLICE;  // t3
  // cheb init: y0 = t3/||t3|| (saved to tb0), y1 -> tb2, ch = ||t3||
  gemv_step<2><<<256, 512, 0, stream>>>(Am, tb1, tb2, cshift, tb0, SLICE;
  int cy = 2, cm = 0;
  for (int k = 0; k < 13; ++k) {
    int co = 3 - cy - cm;
    gemv_step<3><<<256, 512, 0, stream>>>(Am, tb[cy], tb[co], cshift, tb[cm], SLICE;
    cm = cy; cy = co;
  }
  // extraction: u = A * (y_last/||y_last||); lambda = ||u||
  int co = 3 - cy - cm;
  gemv_step<0><<<256, 512, 0, stream>>>(Am, tb[cy], tb[co], cshift, tb[cm], SLICE;
#undef SLICE
  finalize_sigma<<<1, 256, 0, stream>>>(tb[co], inv_scale);

  // out = (x @ W^T) * inv_scale : grid 256, mT=32 (same-A blocks share an XCD)
  gemm256<1><<<256, 512, 0, stream>>>(xb, Wb, out, M, N, K, K, 8, 32, inv_scale);
}

// Round 12
// 168.832 us; speedup vs baseline: 3.6069x; 1.0074x over previous
//
#include <hip/hip_runtime.h>
#include <stdint.h>

typedef short bf16x8 __attribute__((ext_vector_type(8)));
typedef float f32x4 __attribute__((ext_vector_type(4)));

__device__ __forceinline__ unsigned short f2bf(float f) {
  union { float f; unsigned int u; } v; v.f = f;
  unsigned int u = v.u;
  return (unsigned short)((u + 0x7FFFu + ((u >> 16) & 1u)) >> 16);  // RNE
}
__device__ __forceinline__ float bf2f(unsigned short u) {
  union { unsigned int u; float f; } v; v.u = ((unsigned int)u) << 16;
  return v.f;
}
__device__ __forceinline__ void async16(const void* g, void* l) {
  __builtin_amdgcn_global_load_lds(
      (const __attribute__((address_space(1))) unsigned int*)g,
      (__attribute__((address_space(3))) unsigned int*)l, 16, 0, 0);
}
__device__ __forceinline__ void cast8(const float4 a, const float4 b,
                                      unsigned short* dst) {
  union { bf16x8 v; unsigned short s[8]; } o;
  o.s[0] = f2bf(a.x); o.s[1] = f2bf(a.y); o.s[2] = f2bf(a.z); o.s[3] = f2bf(a.w);
  o.s[4] = f2bf(b.x); o.s[5] = f2bf(b.y); o.s[6] = f2bf(b.z); o.s[7] = f2bf(b.w);
  *(bf16x8*)dst = o.v;
}
__device__ __forceinline__ float dot8(bf16x8 a, float4 v0, float4 v1) {
  return bf2f((unsigned short)a[0]) * v0.x + bf2f((unsigned short)a[1]) * v0.y +
         bf2f((unsigned short)a[2]) * v0.z + bf2f((unsigned short)a[3]) * v0.w +
         bf2f((unsigned short)a[4]) * v1.x + bf2f((unsigned short)a[5]) * v1.y +
         bf2f((unsigned short)a[6]) * v1.z + bf2f((unsigned short)a[7]) * v1.w;
}

// ---------------- cast f32 -> bf16, 8 elems/thread (W only) ----------------
__global__ __launch_bounds__(256) void cast_f32_bf16(
    const float* __restrict__ in, unsigned short* __restrict__ out, int n8) {
  int i = blockIdx.x * 256 + threadIdx.x;
  if (i >= n8) return;
  const float4* p = (const float4*)in;
  cast8(p[2 * (size_t)i], p[2 * (size_t)i + 1], out + 8 * (size_t)i);
}

// stage one 16KB chunk (128 rows x 64 cols bf16) into linear LDS, 512 threads.
// Source pre-swizzled (16B chunk j of row r fetches global chunk j^(r&7)):
// swizzled reads then see correct data (both-sides-or-neither).
__device__ __forceinline__ void stage16k(const unsigned short* __restrict__ g0,
                                         int ldK, unsigned short* lds, int tid) {
#pragma unroll
  for (int q = 0; q < 2; ++q) {
    int idx = q * 512 + tid;
    int r = idx >> 3;                 // 0..127
    int jj = (idx & 7) ^ (r & 7);     // swizzled 16B chunk
    async16(g0 + (size_t)r * ldK + jj * 8,
            lds + ((size_t)(q * 512 + (tid & ~63))) * 8);  // wave-uniform base
  }
}

// C[m][n] = sum_k A[m0+m][ks*K + k] * B[n0+n][ks*K + k], both row-major lda.
// BM=BN=256, BK=64, 512 thr = 8 waves (2M x 4N), per-wave 128x64 out.
// 16x16x32 MFMA. kh-PIPELINED inner loop: phase q executes G(q,kh0) with
// just-read frags + G(q-1,kh1) from registers; bg[kh0] read at q0, bg[kh1] at
// q1 -> per-phase LDS reads 8/8/4/4 (was 12/4/4/4, the q0 spike was the pole).
// Per-acc accumulation order (kh0 then kh1) unchanged -> bitwise-identical.
// A triple-buffered, B double-buffered (160KB LDS); vmcnt(8) at ph3/ph7.
// K%128==0, K/128>=2. grid: mb=bid%mT (same-A blocks share XCD),
// nb=(bid/mT)%nTn, ks=bid/(mT*nTn).
// OMODE 1: f32 out * inv_scale computed IN-EPILOGUE from tvec (scale_ptr =
//          2048-float extraction vector; sigma = (sum t^2)^(1/4)).
// OMODE 2: bf16 out at plane ks (split-K partial).
template <int OMODE>
__global__ __launch_bounds__(512, 2) void gemm256(
    const unsigned short* __restrict__ A, const unsigned short* __restrict__ B,
    void* __restrict__ Cv, int M, int N, int lda, int K,
    int nTn, int mT, const float* __restrict__ scale_ptr) {
  __shared__ __align__(16) unsigned short AsBuf[3][256 * 64];  // 96 KB
  __shared__ __align__(16) unsigned short BsBuf[2][256 * 64];  // 64 KB
  const int tid = threadIdx.x;
  const int w = tid >> 6, lane = tid & 63;
  int bid = blockIdx.x;
  const int mb = bid % mT; bid /= mT;
  const int nb = bid % nTn; const int ks = bid / nTn;
  const int m0 = mb * 256, n0 = nb * 256;
  const int wr = w >> 2, wc = w & 3;   // 2M x 4N waves
  const int R = K >> 7;                // iterations (pairs of K-tiles)

  const unsigned short* Ab = A + (size_t)m0 * lda + (size_t)ks * K;
  const unsigned short* Bb = B + (size_t)n0 * lda + (size_t)ks * K;

  unsigned short *a0 = AsBuf[0], *a1 = AsBuf[1], *a2 = AsBuf[2];
  unsigned short *b0 = BsBuf[0], *b1 = BsBuf[1];

  // prologue: A0,B0 then A1,B1 (16 loads/thread); vmcnt(8) -> A0,B0 landed
  stage16k(Ab,                          lda, a0,            tid);
  stage16k(Ab + (size_t)128 * lda,      lda, a0 + 128 * 64, tid);
  stage16k(Bb,                          lda, b0,            tid);
  stage16k(Bb + (size_t)128 * lda,      lda, b0 + 128 * 64, tid);
  stage16k(Ab + 64,                     lda, a1,            tid);
  stage16k(Ab + 64 + (size_t)128 * lda, lda, a1 + 128 * 64, tid);
  stage16k(Bb + 64,                     lda, b1,            tid);
  stage16k(Bb + 64 + (size_t)128 * lda, lda, b1 + 128 * 64, tid);
  asm volatile("s_waitcnt vmcnt(8)" ::: "memory");
  __builtin_amdgcn_s_barrier();
  asm volatile("" ::: "memory");

  const int fr = lane & 15;
  const int bc0 = ((lane >> 4) << 4) ^ ((fr & 7) << 4);  // swizzled k-half 0
  const int bc1 = bc0 ^ 64;                              // k-half 1

  f32x4 acc[8][4] = {};
  bf16x8 bg[4][2] = {};   // B-frags, register-resident across phases
  bf16x8 afp[2] = {};     // previous phase's A-frags (kh=1) for the pipeline

  for (int r = 0; r < R; ++r) {
    const bool st = (r + 1 < R);  // stage tiles 2r+2, 2r+3?
#pragma unroll
    for (int ph = 0; ph < 8; ++ph) {
      const int d = ph >> 2, q = ph & 3;
      const int pq = ((ph + 7) & 7) & 3;  // previous phase's quadrant
      const char* cA = (const char*)(d == 0 ? a0 : a1);
      const char* cB = (const char*)(d == 0 ? b0 : b1);
      if (q == 0) {  // B-frags kh=0 for this K-tile
#pragma unroll
        for (int nf = 0; nf < 4; ++nf) {
          int rb = (wc * 64 + nf * 16 + fr) * 128;
          bg[nf][0] = *(const bf16x8*)(cB + rb + bc0);
        }
      }
      if (q == 1) {  // B-frags kh=1 (first used by G(0,1) this phase)
#pragma unroll
        for (int nf = 0; nf < 4; ++nf) {
          int rb = (wc * 64 + nf * 16 + fr) * 128;
          bg[nf][1] = *(const bf16x8*)(cB + rb + bc1);
        }
      }
      bf16x8 af[2][2];
#pragma unroll
      for (int m2 = 0; m2 < 2; ++m2) {
        int rb = (wr * 128 + q * 32 + m2 * 16 + fr) * 128;
        af[m2][0] = *(const bf16x8*)(cA + rb + bc0);
        af[m2][1] = *(const bf16x8*)(cA + rb + bc1);
      }
      // uniform stage schedule: all targets free (last read >=1 barrier ago),
      // all consumers >=5 phases ahead (covers HBM latency).
      if (st) switch (ph) {
        case 0: stage16k(Ab + (size_t)(2 * r + 2) * 64, lda, a2, tid); break;
        case 1: stage16k(Ab + (size_t)(2 * r + 2) * 64 + (size_t)128 * lda, lda,
                         a2 + 128 * 64, tid); break;
        case 2: stage16k(Bb + (size_t)(2 * r + 2) * 64, lda, b0, tid); break;
        case 3: stage16k(Bb + (size_t)(2 * r + 2) * 64 + (size_t)128 * lda, lda,
                         b0 + 128 * 64, tid); break;
        case 4: stage16k(Ab + (size_t)(2 * r + 3) * 64, lda, a0, tid); break;
        case 5: stage16k(Ab + (size_t)(2 * r + 3) * 64 + (size_t)128 * lda, lda,
                         a0 + 128 * 64, tid); break;
        case 6: stage16k(Bb + (size_t)(2 * r + 3) * 64, lda, b1, tid); break;
        case 7: stage16k(Bb + (size_t)(2 * r + 3) * 64 + (size_t)128 * lda, lda,
                         b1 + 128 * 64, tid); break;
      }
      asm volatile("" ::: "memory");
      __builtin_amdgcn_s_barrier();
      asm volatile("" ::: "memory");
      __builtin_amdgcn_s_setprio(1);
      // G(q, kh=0): just-read fragments
#pragma unroll
      for (int m2 = 0; m2 < 2; ++m2)
#pragma unroll
        for (int nf = 0; nf < 4; ++nf)
          acc[q * 2 + m2][nf] = __builtin_amdgcn_mfma_f32_16x16x32_bf16(
              af[m2][0], bg[nf][0], acc[q * 2 + m2][nf], 0, 0, 0);
      // G(q-1, kh=1): register-resident fragments from the previous phase
      if (ph != 0 || r > 0) {
#pragma unroll
        for (int m2 = 0; m2 < 2; ++m2)
#pragma unroll
          for (int nf = 0; nf < 4; ++nf)
            acc[pq * 2 + m2][nf] = __builtin_amdgcn_mfma_f32_16x16x32_bf16(
                afp[m2], bg[nf][1], acc[pq * 2 + m2][nf], 0, 0, 0);
      }
      __builtin_amdgcn_s_setprio(0);
      afp[0] = af[0][1];
      afp[1] = af[1][1];
      asm volatile("" ::: "memory");
      if (ph == 3) {
        // ph4 reads tiles staged last iter ph4-7 (8 loads = oldest outstanding)
        if (st) asm volatile("s_waitcnt vmcnt(8)" ::: "memory");
        else    asm volatile("s_waitcnt vmcnt(0)" ::: "memory");
      } else if (ph == 7) {
        // next iter ph0 reads tiles staged this iter ph0-3
        if (st) asm volatile("s_waitcnt vmcnt(8)" ::: "memory");
      }
      __builtin_amdgcn_s_barrier();
      asm volatile("" ::: "memory");
    }
    // A-buffer rotation: next iter low tile = a2, high = a0, stage target = a1
    unsigned short* t = a2; a2 = a1; a1 = a0; a0 = t;
  }
  // pipeline drain: G(q=3 of last K-tile, kh=1)
#pragma unroll
  for (int m2 = 0; m2 < 2; ++m2)
#pragma unroll
    for (int nf = 0; nf < 4; ++nf)
      acc[3 * 2 + m2][nf] = __builtin_amdgcn_mfma_f32_16x16x32_bf16(
          afp[m2], bg[nf][1], acc[3 * 2 + m2][nf], 0, 0, 0);

  float sc = 1.0f;
  if (OMODE == 1) {
    // fused finalize: scale_ptr = extraction vector u (2048 f32, ||v||=1
    // input). lambda = ||u|| = sigma^2 -> sigma = (sum u^2)^(1/4).
    // Each wave computes it redundantly (identical order -> deterministic).
    const float4* tvp = (const float4*)scale_ptr;
    float ss = 0.f;
#pragma unroll
    for (int j = 0; j < 8; ++j) {
      float4 v = tvp[lane * 8 + j];
      ss += v.x * v.x + v.y * v.y + v.z * v.z + v.w * v.w;
    }
#pragma unroll
    for (int o = 32; o > 0; o >>= 1) ss += __shfl_xor(ss, o);
    float sigma = sqrtf(sqrtf(ss));
    sc = 1.0f / fmaxf(sigma, 1.0f);  // BOUND = 1.0
  }
  size_t base = (OMODE == 2) ? (size_t)ks * ((size_t)M * N) : 0;
  // C/D layout: col = lane&15, row = (lane>>4)*4 + reg (verified)
  const int rr0 = m0 + wr * 128 + ((lane >> 4) << 2);
  const int cc0 = n0 + wc * 64 + fr;
#pragma unroll
  for (int mf = 0; mf < 8; ++mf)
#pragma unroll
    for (int nf = 0; nf < 4; ++nf)
#pragma unroll
      for (int tt = 0; tt < 4; ++tt) {
        size_t idx = base + (size_t)(rr0 + mf * 16 + tt) * N + (cc0 + nf * 16);
        if (OMODE == 2) ((unsigned short*)Cv)[idx] = f2bf(acc[mf][nf][tt]);
        else            ((float*)Cv)[idx] = acc[mf][nf][tt] * sc;
      }
}

// ---- fused: reduce 4 split-K planes -> Am (bf16, in-place on plane 0),
// ---- init t0 (hash, normalized), and rough power step #1: tout = A_sum v0.
__global__ __launch_bounds__(512) void gemv_first(
    const unsigned short* __restrict__ P, unsigned short* __restrict__ Aout,
    size_t plane, float* __restrict__ tout) {
  __shared__ __align__(16) float vs[2048];
  __shared__ float wred[8];
  const int tid = threadIdx.x;
  const int wv = tid >> 6, lane = tid & 63;
  const int row = blockIdx.x * 8 + wv;

  // t0 via deterministic hash (4 elems/thread), redundant per-block norm
  float t0[4]; float ss = 0.f;
#pragma unroll
  for (int j = 0; j < 4; ++j) {
    int idx = tid * 4 + j;
    unsigned int h = (unsigned int)idx * 2654435761u;
    h ^= h >> 16; h *= 2246822519u; h ^= h >> 13;
    t0[j] = (float)(h & 0xFFFFu) * (1.0f / 65536.0f) - 0.5f;
    ss += t0[j] * t0[j];
  }
#pragma unroll
  for (int o = 32; o > 0; o >>= 1) ss += __shfl_xor(ss, o);
  if (lane == 0) wred[wv] = ss;
  __syncthreads();
  float n2 = 0.f;
#pragma unroll
  for (int j = 0; j < 8; ++j) n2 += wred[j];
  float inv = 1.0f / sqrtf(n2);
#pragma unroll
  for (int j = 0; j < 4; ++j) vs[tid * 4 + j] = t0[j] * inv;
  __syncthreads();

  const size_t rbase = (size_t)row * 2048;
  float s = 0.f;
#pragma unroll
  for (int c4 = 0; c4 < 4; ++c4) {
    int c = lane + c4 * 64;  // 16B chunk index 0..255 within the row
    float a8[8] = {0.f, 0.f, 0.f, 0.f, 0.f, 0.f, 0.f, 0.f};
#pragma unroll
    for (int p = 0; p < 4; ++p) {
      bf16x8 v = *(const bf16x8*)(P + p * plane + rbase + (size_t)c * 8);
#pragma unroll
      for (int j = 0; j < 8; ++j) a8[j] += bf2f((unsigned short)v[j]);
    }
    union { bf16x8 v; unsigned short u[8]; } o;
#pragma unroll
    for (int j = 0; j < 8; ++j) o.u[j] = f2bf(a8[j]);
    *(bf16x8*)(Aout + rbase + (size_t)c * 8) = o.v;
    float4 v0 = ((const float4*)vs)[2 * c], v1 = ((const float4*)vs)[2 * c + 1];
    s += a8[0] * v0.x + a8[1] * v0.y + a8[2] * v0.z + a8[3] * v0.w +
         a8[4] * v1.x + a8[5] * v1.y + a8[6] * v1.z + a8[7] * v1.w;
  }
#pragma unroll
  for (int o = 32; o > 0; o >>= 1) s += __shfl_xor(s, o);
  if (lane == 0) tout[row] = s;
}

// ---------------- GEMV step on A (2048x2048 bf16), 256 blocks x 512 thr ----
// MODE 0 (plain):  v = tin/||tin||;          tout[row] = (A v)[row]
// MODE 2 (cheb-init): rho=||tin||; v=tin/rho; tout[row] = (2/rho)(Av)[row]-v[row];
//                   aux[row] = v[row] (y0 for the next step); ch[0] = rho (blk 0)
// MODE 3 (cheb):   v = tin (raw);            tout[row] = (4/ch)(Av)[row]
//                                                        - 2 v[row] - aux[row]
template <int MODE>
__global__ __launch_bounds__(512) void gemv_step(
    const unsigned short* __restrict__ Am, const float* __restrict__ tin,
    float* __restrict__ tout, float* __restrict__ ch, float* __restrict__ aux,
    const float* __restrict__ xsrc, unsigned short* __restrict__ xdst,
    int u0, int u1) {
  __shared__ __align__(16) float vs[2048];
  __shared__ float wred[8];
  const int tid = threadIdx.x;
  const int wv = tid >> 6, lane = tid & 63;
  const int row = blockIdx.x * 8 + wv;

  // early-issue: A-row chunks (independent of the norm path -> in flight now)
  const bf16x8* Ar = (const bf16x8*)(Am + (size_t)row * 2048);
  bf16x8 ar0 = Ar[lane], ar1 = Ar[lane + 64];
  bf16x8 ar2 = Ar[lane + 128], ar3 = Ar[lane + 192];
  // early-issue: x-cast slice (2 guarded units/thread)
  const int cu0 = u0 + blockIdx.x * 512 + tid;
  const int cu1 = cu0 + 131072;
  const bool cd0 = cu0 < u1, cd1 = cu1 < u1;
  float4 ca0, cb0, ca1, cb1;
  const float4* xp = (const float4*)xsrc;
  if (cd0) { ca0 = xp[2 * (size_t)cu0]; cb0 = xp[2 * (size_t)cu0 + 1]; }
  if (cd1) { ca1 = xp[2 * (size_t)cu1]; cb1 = xp[2 * (size_t)cu1 + 1]; }

  float ymv = 0.f, chv = 0.f;
  if (MODE == 3) { ymv = aux[row]; chv = ch[0]; }

  float4 x0 = ((const float4*)tin)[tid];
  float sin_ = 1.0f;
  if (MODE != 3) {  // redundant deterministic norm (identical in every block)
    float ss = x0.x * x0.x + x0.y * x0.y + x0.z * x0.z + x0.w * x0.w;
#pragma unroll
    for (int o = 32; o > 0; o >>= 1) ss += __shfl_xor(ss, o);
    if (lane == 0) wred[wv] = ss;
    __syncthreads();
    float n2 = 0.f;
#pragma unroll
    for (int j = 0; j < 8; ++j) n2 += wred[j];
    float nrm = sqrtf(n2);
    if (MODE == 2) {
      chv = nrm;
      if (blockIdx.x == 0 && tid == 0) ch[0] = nrm;
    }
    sin_ = 1.0f / nrm;
  }
  float4 y = {x0.x * sin_, x0.y * sin_, x0.z * sin_, x0.w * sin_};
  ((float4*)vs)[tid] = y;
  __syncthreads();

  const float4* vp = (const float4*)vs;
  float s = dot8(ar0, vp[2 * lane], vp[2 * lane + 1]);
  s += dot8(ar1, vp[2 * (lane + 64)], vp[2 * (lane + 64) + 1]);
  s += dot8(ar2, vp[2 * (lane + 128)], vp[2 * (lane + 128) + 1]);
  s += dot8(ar3, vp[2 * (lane + 192)], vp[2 * (lane + 192) + 1]);
#pragma unroll
  for (int o = 32; o > 0; o >>= 1) s += __shfl_xor(s, o);
  if (lane == 0) {
    float r;
    if (MODE == 0)      r = s;
    else if (MODE == 2) r = (2.0f / chv) * s - vs[row];
    else                r = (4.0f / chv) * s - 2.0f * vs[row] - ymv;
    tout[row] = r;
    if (MODE == 2) aux[row] = vs[row];  // y0 (normalized) for first cheb step
  }
  // distributed x-cast writeback
  if (cd0) cast8(ca0, cb0, xdst + 8 * (size_t)cu0);
  if (cd1) cast8(ca1, cb1, xdst + 8 * (size_t)cu1);
}

extern "C" void kernel_launch(void* const* d_in, const int* in_sizes, int n_in,
                              void* d_out, int out_size, void* d_ws, size_t ws_size,
                              hipStream_t stream) {
  (void)in_sizes; (void)n_in; (void)out_size; (void)ws_size;
  const float* x = (const float*)d_in[0];   // [8192, 2048]
  const float* W = (const float*)d_in[1];   // [2048, 2048]
  float* out = (float*)d_out;
  char* ws = (char*)d_ws;
  const int K = 2048, N = 2048, M = 4 * 2048;
  const size_t PLANE = (size_t)2048 * 2048;  // elems per bf16 plane (8 MB)

  unsigned short* xb = (unsigned short*)(ws);                       // 0-32 MB
  unsigned short* Wb = (unsigned short*)(ws + ((size_t)32 << 20));  // 32-40 MB
  unsigned short* P1 = (unsigned short*)(ws + ((size_t)40 << 20));  // 40-72 MB (4 planes)
  unsigned short* Am = P1;                                          // in-place reduce
  float* tv = (float*)(ws + ((size_t)72 << 20));
  float* tb0 = tv, *tb1 = tv + 2048, *tb2 = tv + 4096;
  float* cshift = tv + 6146;
  float* tb[3] = {tb0, tb1, tb2};

  // W-cast only; x-cast is distributed across the 17 light GEMV launches
  cast_f32_bf16<<<(N * K / 8 + 255) / 256, 256, 0, stream>>>(W, Wb, N * K / 8);

  // A = W W^T (sigma^2): split-K=4, grid 256
  gemm256<2><<<256, 512, 0, stream>>>(Wb, Wb, P1, 2048, 2048, 2048, 512, 8, 8, nullptr);
  // fused plane-reduce + t0 init + rough power step #1 -> tb1
  gemv_first<<<256, 512, 0, stream>>>(P1, Am, PLANE, tb1);

  // sigma estimation (R9-proven depth): rough #2, #3 -> cheb-init
  // (lambda_hat = ||t3||) -> 13x cheb -> extraction GEMV. 17 light launches.
  const int XU = M * K / 8;             // 2,097,152 cast units
  const int NL = 17;
  const int CH = (XU + NL - 1) / NL;    // per-launch slice
  int li = 0;
#define SLICE x, xb, (li) * CH, min((li + 1) * CH, XU)); ++li
  gemv_step<0><<<256, 512, 0, stream>>>(Am, tb1, tb0, cshift, tb2, SLICE;  // t2
  gemv_step<0><<<256, 512, 0, stream>>>(Am, tb0, tb1, cshift, tb2, SLICE;  // t3
  // cheb init: y0 = t3/||t3|| (saved to tb0), y1 -> tb2, ch = ||t3||
  gemv_step<2><<<256, 512, 0, stream>>>(Am, tb1, tb2, cshift, tb0, SLICE;
  int cy = 2, cm = 0;
  for (int k = 0; k < 13; ++k) {
    int co = 3 - cy - cm;
    gemv_step<3><<<256, 512, 0, stream>>>(Am, tb[cy], tb[co], cshift, tb[cm], SLICE;
    cm = cy; cy = co;
  }
  // extraction: u = A * (y_last/||y_last||); lambda = ||u|| (consumed by the
  // main GEMM's fused-finalize epilogue)
  int co = 3 - cy - cm;
  gemv_step<0><<<256, 512, 0, stream>>>(Am, tb[cy], tb[co], cshift, tb[cm], SLICE;
#undef SLICE

  // out = (x @ W^T) * inv_scale : grid 256, mT=32 (same-A blocks share an XCD)
  // scale_ptr = extraction vector (finalize fused into the epilogue)
  gemm256<1><<<256, 512, 0, stream>>>(xb, Wb, out, M, N, K, K, 8, 32, tb[co]);
}

// Round 13
// 168.793 us; speedup vs baseline: 3.6078x; 1.0002x over previous
//
#include <hip/hip_runtime.h>
#include <stdint.h>

typedef short bf16x8 __attribute__((ext_vector_type(8)));
typedef float f32x4 __attribute__((ext_vector_type(4)));

__device__ __forceinline__ unsigned short f2bf(float f) {
  union { float f; unsigned int u; } v; v.f = f;
  unsigned int u = v.u;
  return (unsigned short)((u + 0x7FFFu + ((u >> 16) & 1u)) >> 16);  // RNE
}
__device__ __forceinline__ float bf2f(unsigned short u) {
  union { unsigned int u; float f; } v; v.u = ((unsigned int)u) << 16;
  return v.f;
}
__device__ __forceinline__ void async16(const void* g, void* l) {
  __builtin_amdgcn_global_load_lds(
      (const __attribute__((address_space(1))) unsigned int*)g,
      (__attribute__((address_space(3))) unsigned int*)l, 16, 0, 0);
}
__device__ __forceinline__ void cast8(const float4 a, const float4 b,
                                      unsigned short* dst) {
  union { bf16x8 v; unsigned short s[8]; } o;
  o.s[0] = f2bf(a.x); o.s[1] = f2bf(a.y); o.s[2] = f2bf(a.z); o.s[3] = f2bf(a.w);
  o.s[4] = f2bf(b.x); o.s[5] = f2bf(b.y); o.s[6] = f2bf(b.z); o.s[7] = f2bf(b.w);
  *(bf16x8*)dst = o.v;
}
__device__ __forceinline__ float dot8(bf16x8 a, float4 v0, float4 v1) {
  return bf2f((unsigned short)a[0]) * v0.x + bf2f((unsigned short)a[1]) * v0.y +
         bf2f((unsigned short)a[2]) * v0.z + bf2f((unsigned short)a[3]) * v0.w +
         bf2f((unsigned short)a[4]) * v1.x + bf2f((unsigned short)a[5]) * v1.y +
         bf2f((unsigned short)a[6]) * v1.z + bf2f((unsigned short)a[7]) * v1.w;
}

// ---------------- cast f32 -> bf16, 8 elems/thread (W only) ----------------
__global__ __launch_bounds__(256) void cast_f32_bf16(
    const float* __restrict__ in, unsigned short* __restrict__ out, int n8) {
  int i = blockIdx.x * 256 + threadIdx.x;
  if (i >= n8) return;
  const float4* p = (const float4*)in;
  cast8(p[2 * (size_t)i], p[2 * (size_t)i + 1], out + 8 * (size_t)i);
}

// stage one 16KB chunk (128 rows x 64 cols bf16) into linear LDS, 512 threads.
// Source pre-swizzled (16B chunk j of row r fetches global chunk j^(r&7)):
// swizzled reads then see correct data (both-sides-or-neither).
__device__ __forceinline__ void stage16k(const unsigned short* __restrict__ g0,
                                         int ldK, unsigned short* lds, int tid) {
#pragma unroll
  for (int q = 0; q < 2; ++q) {
    int idx = q * 512 + tid;
    int r = idx >> 3;                 // 0..127
    int jj = (idx & 7) ^ (r & 7);     // swizzled 16B chunk
    async16(g0 + (size_t)r * ldK + jj * 8,
            lds + ((size_t)(q * 512 + (tid & ~63))) * 8);  // wave-uniform base
  }
}

// C[m][n] = sum_k A[m0+m][ks*K + k] * B[n0+n][ks*K + k], both row-major lda.
// BM=BN=256, BK=64, 512 thr = 8 waves (2M x 4N), per-wave 128x64 out.
// 16x16x32 MFMA (R5/R11-proven inner loop: 0 bank conflicts, 112 VGPR,
// 75 us @ main shape — kh-pipeline variant measured slower, reverted).
// A triple-buffered, B double-buffered (160KB LDS); every chunk staged >=5
// phases before use; vmcnt(8) at ph3/ph7. K%128==0, K/128>=2.
// grid decode: mb = bid%mT (same-A blocks share an XCD), nb=(bid/mT)%nTn,
// ks = bid/(mT*nTn).
// OMODE 1: f32 out * inv_scale computed IN-EPILOGUE from scale_ptr =
//          2048-float extraction vector u (||v||=1): sigma = (sum u^2)^(1/4).
// OMODE 2: bf16 out at plane ks (split-K partial).
template <int OMODE>
__global__ __launch_bounds__(512, 2) void gemm256(
    const unsigned short* __restrict__ A, const unsigned short* __restrict__ B,
    void* __restrict__ Cv, int M, int N, int lda, int K,
    int nTn, int mT, const float* __restrict__ scale_ptr) {
  __shared__ __align__(16) unsigned short AsBuf[3][256 * 64];  // 96 KB
  __shared__ __align__(16) unsigned short BsBuf[2][256 * 64];  // 64 KB
  const int tid = threadIdx.x;
  const int w = tid >> 6, lane = tid & 63;
  int bid = blockIdx.x;
  const int mb = bid % mT; bid /= mT;
  const int nb = bid % nTn; const int ks = bid / nTn;
  const int m0 = mb * 256, n0 = nb * 256;
  const int wr = w >> 2, wc = w & 3;   // 2M x 4N waves
  const int R = K >> 7;                // iterations (pairs of K-tiles)

  const unsigned short* Ab = A + (size_t)m0 * lda + (size_t)ks * K;
  const unsigned short* Bb = B + (size_t)n0 * lda + (size_t)ks * K;

  unsigned short *a0 = AsBuf[0], *a1 = AsBuf[1], *a2 = AsBuf[2];
  unsigned short *b0 = BsBuf[0], *b1 = BsBuf[1];

  // prologue: A0,B0 then A1,B1 (16 loads/thread); vmcnt(8) -> A0,B0 landed
  stage16k(Ab,                          lda, a0,            tid);
  stage16k(Ab + (size_t)128 * lda,      lda, a0 + 128 * 64, tid);
  stage16k(Bb,                          lda, b0,            tid);
  stage16k(Bb + (size_t)128 * lda,      lda, b0 + 128 * 64, tid);
  stage16k(Ab + 64,                     lda, a1,            tid);
  stage16k(Ab + 64 + (size_t)128 * lda, lda, a1 + 128 * 64, tid);
  stage16k(Bb + 64,                     lda, b1,            tid);
  stage16k(Bb + 64 + (size_t)128 * lda, lda, b1 + 128 * 64, tid);
  asm volatile("s_waitcnt vmcnt(8)" ::: "memory");
  __builtin_amdgcn_s_barrier();
  asm volatile("" ::: "memory");

  const int fr = lane & 15;
  const int bc0 = ((lane >> 4) << 4) ^ ((fr & 7) << 4);  // swizzled k-half 0
  const int bc1 = bc0 ^ 64;                              // k-half 1

  f32x4 acc[8][4] = {};

  for (int r = 0; r < R; ++r) {
    const bool st = (r + 1 < R);  // stage tiles 2r+2, 2r+3?
    bf16x8 bg[4][2];
#pragma unroll
    for (int ph = 0; ph < 8; ++ph) {
      const int d = ph >> 2, q = ph & 3;
      const char* cA = (const char*)(d == 0 ? a0 : a1);
      const char* cB = (const char*)(d == 0 ? b0 : b1);
      if (q == 0) {  // B-frags for this K-tile, register-resident 4 phases
#pragma unroll
        for (int nf = 0; nf < 4; ++nf) {
          int rb = (wc * 64 + nf * 16 + fr) * 128;
          bg[nf][0] = *(const bf16x8*)(cB + rb + bc0);
          bg[nf][1] = *(const bf16x8*)(cB + rb + bc1);
        }
      }
      bf16x8 af[2][2];
#pragma unroll
      for (int m2 = 0; m2 < 2; ++m2) {
        int rb = (wr * 128 + q * 32 + m2 * 16 + fr) * 128;
        af[m2][0] = *(const bf16x8*)(cA + rb + bc0);
        af[m2][1] = *(const bf16x8*)(cA + rb + bc1);
      }
      // uniform stage schedule: all targets free (last read >=1 barrier ago),
      // all consumers >=5 phases ahead (covers HBM latency).
      if (st) switch (ph) {
        case 0: stage16k(Ab + (size_t)(2 * r + 2) * 64, lda, a2, tid); break;
        case 1: stage16k(Ab + (size_t)(2 * r + 2) * 64 + (size_t)128 * lda, lda,
                         a2 + 128 * 64, tid); break;
        case 2: stage16k(Bb + (size_t)(2 * r + 2) * 64, lda, b0, tid); break;
        case 3: stage16k(Bb + (size_t)(2 * r + 2) * 64 + (size_t)128 * lda, lda,
                         b0 + 128 * 64, tid); break;
        case 4: stage16k(Ab + (size_t)(2 * r + 3) * 64, lda, a0, tid); break;
        case 5: stage16k(Ab + (size_t)(2 * r + 3) * 64 + (size_t)128 * lda, lda,
                         a0 + 128 * 64, tid); break;
        case 6: stage16k(Bb + (size_t)(2 * r + 3) * 64, lda, b1, tid); break;
        case 7: stage16k(Bb + (size_t)(2 * r + 3) * 64 + (size_t)128 * lda, lda,
                         b1 + 128 * 64, tid); break;
      }
      asm volatile("" ::: "memory");
      __builtin_amdgcn_s_barrier();
      asm volatile("" ::: "memory");
      __builtin_amdgcn_s_setprio(1);
#pragma unroll
      for (int m2 = 0; m2 < 2; ++m2)
#pragma unroll
        for (int nf = 0; nf < 4; ++nf)
#pragma unroll
          for (int kh = 0; kh < 2; ++kh)
            acc[q * 2 + m2][nf] = __builtin_amdgcn_mfma_f32_16x16x32_bf16(
                af[m2][kh], bg[nf][kh], acc[q * 2 + m2][nf], 0, 0, 0);
      __builtin_amdgcn_s_setprio(0);
      asm volatile("" ::: "memory");
      if (ph == 3) {
        // ph4 reads tiles staged last iter ph4-7 (8 loads = oldest outstanding)
        if (st) asm volatile("s_waitcnt vmcnt(8)" ::: "memory");
        else    asm volatile("s_waitcnt vmcnt(0)" ::: "memory");
      } else if (ph == 7) {
        // next iter ph0 reads tiles staged this iter ph0-3
        if (st) asm volatile("s_waitcnt vmcnt(8)" ::: "memory");
      }
      __builtin_amdgcn_s_barrier();
      asm volatile("" ::: "memory");
    }
    // A-buffer rotation: next iter low tile = a2, high = a0, stage target = a1
    unsigned short* t = a2; a2 = a1; a1 = a0; a0 = t;
  }

  float sc = 1.0f;
  if (OMODE == 1) {
    // fused finalize: lambda = ||u|| = sigma^2 -> sigma = (sum u^2)^(1/4).
    // Each wave computes it redundantly (identical order -> deterministic).
    const float4* tvp = (const float4*)scale_ptr;
    float ss = 0.f;
#pragma unroll
    for (int j = 0; j < 8; ++j) {
      float4 v = tvp[lane * 8 + j];
      ss += v.x * v.x + v.y * v.y + v.z * v.z + v.w * v.w;
    }
#pragma unroll
    for (int o = 32; o > 0; o >>= 1) ss += __shfl_xor(ss, o);
    float sigma = sqrtf(sqrtf(ss));
    sc = 1.0f / fmaxf(sigma, 1.0f);  // BOUND = 1.0
  }
  size_t base = (OMODE == 2) ? (size_t)ks * ((size_t)M * N) : 0;
  // C/D layout: col = lane&15, row = (lane>>4)*4 + reg (verified)
  const int rr0 = m0 + wr * 128 + ((lane >> 4) << 2);
  const int cc0 = n0 + wc * 64 + fr;
#pragma unroll
  for (int mf = 0; mf < 8; ++mf)
#pragma unroll
    for (int nf = 0; nf < 4; ++nf)
#pragma unroll
      for (int tt = 0; tt < 4; ++tt) {
        size_t idx = base + (size_t)(rr0 + mf * 16 + tt) * N + (cc0 + nf * 16);
        if (OMODE == 2) ((unsigned short*)Cv)[idx] = f2bf(acc[mf][nf][tt]);
        else            ((float*)Cv)[idx] = acc[mf][nf][tt] * sc;
      }
}

// ---- fused: reduce 4 split-K planes -> Am (bf16, in-place on plane 0),
// ---- init t0 (hash, normalized), and rough power step #1: tout = A_sum v0.
__global__ __launch_bounds__(512) void gemv_first(
    const unsigned short* __restrict__ P, unsigned short* __restrict__ Aout,
    size_t plane, float* __restrict__ tout) {
  __shared__ __align__(16) float vs[2048];
  __shared__ float wred[8];
  const int tid = threadIdx.x;
  const int wv = tid >> 6, lane = tid & 63;
  const int row = blockIdx.x * 8 + wv;

  // t0 via deterministic hash (4 elems/thread), redundant per-block norm
  float t0[4]; float ss = 0.f;
#pragma unroll
  for (int j = 0; j < 4; ++j) {
    int idx = tid * 4 + j;
    unsigned int h = (unsigned int)idx * 2654435761u;
    h ^= h >> 16; h *= 2246822519u; h ^= h >> 13;
    t0[j] = (float)(h & 0xFFFFu) * (1.0f / 65536.0f) - 0.5f;
    ss += t0[j] * t0[j];
  }
#pragma unroll
  for (int o = 32; o > 0; o >>= 1) ss += __shfl_xor(ss, o);
  if (lane == 0) wred[wv] = ss;
  __syncthreads();
  float n2 = 0.f;
#pragma unroll
  for (int j = 0; j < 8; ++j) n2 += wred[j];
  float inv = 1.0f / sqrtf(n2);
#pragma unroll
  for (int j = 0; j < 4; ++j) vs[tid * 4 + j] = t0[j] * inv;
  __syncthreads();

  const size_t rbase = (size_t)row * 2048;
  float s = 0.f;
#pragma unroll
  for (int c4 = 0; c4 < 4; ++c4) {
    int c = lane + c4 * 64;  // 16B chunk index 0..255 within the row
    float a8[8] = {0.f, 0.f, 0.f, 0.f, 0.f, 0.f, 0.f, 0.f};
#pragma unroll
    for (int p = 0; p < 4; ++p) {
      bf16x8 v = *(const bf16x8*)(P + p * plane + rbase + (size_t)c * 8);
#pragma unroll
      for (int j = 0; j < 8; ++j) a8[j] += bf2f((unsigned short)v[j]);
    }
    union { bf16x8 v; unsigned short u[8]; } o;
#pragma unroll
    for (int j = 0; j < 8; ++j) o.u[j] = f2bf(a8[j]);
    *(bf16x8*)(Aout + rbase + (size_t)c * 8) = o.v;
    float4 v0 = ((const float4*)vs)[2 * c], v1 = ((const float4*)vs)[2 * c + 1];
    s += a8[0] * v0.x + a8[1] * v0.y + a8[2] * v0.z + a8[3] * v0.w +
         a8[4] * v1.x + a8[5] * v1.y + a8[6] * v1.z + a8[7] * v1.w;
  }
#pragma unroll
  for (int o = 32; o > 0; o >>= 1) s += __shfl_xor(s, o);
  if (lane == 0) tout[row] = s;
}

// ---------------- GEMV step on A (2048x2048 bf16), 256 blocks x 512 thr ----
// MODE 0 (plain):  v = tin/||tin||;          tout[row] = (A v)[row]
// MODE 2 (cheb-init): rho=||tin||; v=tin/rho; tout[row] = (2/rho)(Av)[row]-v[row];
//                   aux[row] = v[row] (y0 for the next step); ch[0] = rho (blk 0)
// MODE 3 (cheb):   v = tin (raw);            tout[row] = (4/ch)(Av)[row]
//                                                        - 2 v[row] - aux[row]
template <int MODE>
__global__ __launch_bounds__(512) void gemv_step(
    const unsigned short* __restrict__ Am, const float* __restrict__ tin,
    float* __restrict__ tout, float* __restrict__ ch, float* __restrict__ aux,
    const float* __restrict__ xsrc, unsigned short* __restrict__ xdst,
    int u0, int u1) {
  __shared__ __align__(16) float vs[2048];
  __shared__ float wred[8];
  const int tid = threadIdx.x;
  const int wv = tid >> 6, lane = tid & 63;
  const int row = blockIdx.x * 8 + wv;

  // early-issue: A-row chunks (independent of the norm path -> in flight now)
  const bf16x8* Ar = (const bf16x8*)(Am + (size_t)row * 2048);
  bf16x8 ar0 = Ar[lane], ar1 = Ar[lane + 64];
  bf16x8 ar2 = Ar[lane + 128], ar3 = Ar[lane + 192];
  // early-issue: x-cast slice (2 guarded units/thread)
  const int cu0 = u0 + blockIdx.x * 512 + tid;
  const int cu1 = cu0 + 131072;
  const bool cd0 = cu0 < u1, cd1 = cu1 < u1;
  float4 ca0, cb0, ca1, cb1;
  const float4* xp = (const float4*)xsrc;
  if (cd0) { ca0 = xp[2 * (size_t)cu0]; cb0 = xp[2 * (size_t)cu0 + 1]; }
  if (cd1) { ca1 = xp[2 * (size_t)cu1]; cb1 = xp[2 * (size_t)cu1 + 1]; }

  float ymv = 0.f, chv = 0.f;
  if (MODE == 3) { ymv = aux[row]; chv = ch[0]; }

  float4 x0 = ((const float4*)tin)[tid];
  float sin_ = 1.0f;
  if (MODE != 3) {  // redundant deterministic norm (identical in every block)
    float ss = x0.x * x0.x + x0.y * x0.y + x0.z * x0.z + x0.w * x0.w;
#pragma unroll
    for (int o = 32; o > 0; o >>= 1) ss += __shfl_xor(ss, o);
    if (lane == 0) wred[wv] = ss;
    __syncthreads();
    float n2 = 0.f;
#pragma unroll
    for (int j = 0; j < 8; ++j) n2 += wred[j];
    float nrm = sqrtf(n2);
    if (MODE == 2) {
      chv = nrm;
      if (blockIdx.x == 0 && tid == 0) ch[0] = nrm;
    }
    sin_ = 1.0f / nrm;
  }
  float4 y = {x0.x * sin_, x0.y * sin_, x0.z * sin_, x0.w * sin_};
  ((float4*)vs)[tid] = y;
  __syncthreads();

  const float4* vp = (const float4*)vs;
  float s = dot8(ar0, vp[2 * lane], vp[2 * lane + 1]);
  s += dot8(ar1, vp[2 * (lane + 64)], vp[2 * (lane + 64) + 1]);
  s += dot8(ar2, vp[2 * (lane + 128)], vp[2 * (lane + 128) + 1]);
  s += dot8(ar3, vp[2 * (lane + 192)], vp[2 * (lane + 192) + 1]);
#pragma unroll
  for (int o = 16; o > 0; o >>= 1) s += __shfl_xor(s, o);
#pragma unroll
  for (int o = 32; o > 16; o >>= 1) s += __shfl_xor(s, o);
  if (lane == 0) {
    float r;
    if (MODE == 0)      r = s;
    else if (MODE == 2) r = (2.0f / chv) * s - vs[row];
    else                r = (4.0f / chv) * s - 2.0f * vs[row] - ymv;
    tout[row] = r;
    if (MODE == 2) aux[row] = vs[row];  // y0 (normalized) for first cheb step
  }
  // distributed x-cast writeback
  if (cd0) cast8(ca0, cb0, xdst + 8 * (size_t)cu0);
  if (cd1) cast8(ca1, cb1, xdst + 8 * (size_t)cu1);
}

extern "C" void kernel_launch(void* const* d_in, const int* in_sizes, int n_in,
                              void* d_out, int out_size, void* d_ws, size_t ws_size,
                              hipStream_t stream) {
  (void)in_sizes; (void)n_in; (void)out_size; (void)ws_size;
  const float* x = (const float*)d_in[0];   // [8192, 2048]
  const float* W = (const float*)d_in[1];   // [2048, 2048]
  float* out = (float*)d_out;
  char* ws = (char*)d_ws;
  const int K = 2048, N = 2048, M = 4 * 2048;
  const size_t PLANE = (size_t)2048 * 2048;  // elems per bf16 plane (8 MB)

  unsigned short* xb = (unsigned short*)(ws);                       // 0-32 MB
  unsigned short* Wb = (unsigned short*)(ws + ((size_t)32 << 20));  // 32-40 MB
  unsigned short* P1 = (unsigned short*)(ws + ((size_t)40 << 20));  // 40-72 MB (4 planes)
  unsigned short* Am = P1;                                          // in-place reduce
  float* tv = (float*)(ws + ((size_t)72 << 20));
  float* tb0 = tv, *tb1 = tv + 2048, *tb2 = tv + 4096;
  float* cshift = tv + 6146;
  float* tb[3] = {tb0, tb1, tb2};

  // W-cast only; x-cast is distributed across the 17 light GEMV launches
  cast_f32_bf16<<<(N * K / 8 + 255) / 256, 256, 0, stream>>>(W, Wb, N * K / 8);

  // A = W W^T (sigma^2): split-K=4, grid 256
  gemm256<2><<<256, 512, 0, stream>>>(Wb, Wb, P1, 2048, 2048, 2048, 512, 8, 8, nullptr);
  // fused plane-reduce + t0 init + rough power step #1 -> tb1
  gemv_first<<<256, 512, 0, stream>>>(P1, Am, PLANE, tb1);

  // sigma estimation (R9/R11-proven depth): rough #2, #3 -> cheb-init
  // (lambda_hat = ||t3||) -> 13x cheb -> extraction GEMV. 17 light launches.
  const int XU = M * K / 8;             // 2,097,152 cast units
  const int NL = 17;
  const int CH = (XU + NL - 1) / NL;    // per-launch slice
  int li = 0;
#define SLICE x, xb, (li) * CH, min((li + 1) * CH, XU)); ++li
  gemv_step<0><<<256, 512, 0, stream>>>(Am, tb1, tb0, cshift, tb2, SLICE;  // t2
  gemv_step<0><<<256, 512, 0, stream>>>(Am, tb0, tb1, cshift, tb2, SLICE;  // t3
  // cheb init: y0 = t3/||t3|| (saved to tb0), y1 -> tb2, ch = ||t3||
  gemv_step<2><<<256, 512, 0, stream>>>(Am, tb1, tb2, cshift, tb0, SLICE;
  int cy = 2, cm = 0;
  for (int k = 0; k < 13; ++k) {
    int co = 3 - cy - cm;
    gemv_step<3><<<256, 512, 0, stream>>>(Am, tb[cy], tb[co], cshift, tb[cm], SLICE;
    cm = cy; cy = co;
  }
  // extraction: u = A * (y_last/||y_last||); lambda = ||u|| (consumed by the
  // main GEMM's fused-finalize epilogue)
  int co = 3 - cy - cm;
  gemv_step<0><<<256, 512, 0, stream>>>(Am, tb[cy], tb[co], cshift, tb[cm], SLICE;
#undef SLICE

  // out = (x @ W^T) * inv_scale : grid 256, mT=32 (same-A blocks share an XCD)
  // scale_ptr = extraction vector (finalize fused into the epilogue)
  gemm256<1><<<256, 512, 0, stream>>>(xb, Wb, out, M, N, K, K, 8, 32, tb[co]);
}